// Round 2
// baseline (3999.120 us; speedup 1.0000x reference)
//
#include <hip/hip_runtime.h>
#include <cstdint>
#include <cstddef>

// ---------------- workspace layout (floats) ----------------
static const size_t OFF_E1    = 0;         // [4,16,256,256]
static const size_t OFF_E2    = 4194304;   // [4,32,128,128]
static const size_t OFF_E3A   = 6291456;   // [4,64,64,64]
static const size_t OFF_E3B   = 7340032;   // [4,64,64,64]
static const size_t OFF_BIG16 = 8388608;   // s1 then unused
static const size_t OFF_BIG8  = 12582912;  // s2 then d3
static const size_t OFF_B4    = 14680064;  // s3 then bn-out
static const size_t OFF_V     = 15728640;  // [4,64,4096]
static const size_t OFF_Q     = 16777216;  // [4,4096,8] transposed
static const size_t OFF_K     = 16908288;  // [4,4096,8] transposed
static const size_t OFF_POOL  = 17039360;
static const size_t OFF_SF1   = 17055744;
static const size_t OFF_SF2   = 17056000;
static const size_t OFF_ROW   = 17056256;
static const size_t OFF_D2LF  = 17072640;  // [4,16,256,256]
static const size_t OFF_PRE   = 21266944;  // [4,3,256,256]

// ================= conv 3x3 s1 p1, register-tiled (4 outputs/thread) ========
// block: (b*Cout + co, oh_tile). ncol = W/4 threads per row, ROWS = 256/ncol.
// in2 may be spatially-broadcast (style_feat). mix: out = 0.99*in1 + 0.01*relu(acc)
__global__ __launch_bounds__(256) void k_conv3x3(
    const float* __restrict__ in1, int C1,
    const float* __restrict__ in2, int C2, int bcast2,
    const float* __restrict__ w, const float* __restrict__ bias,
    float* __restrict__ out, int B, int H, int W, int Cout, int relu, int mix)
{
  int ncol = W >> 2;
  int tid = threadIdx.x;
  int tx = tid % ncol, ty = tid / ncol;
  int ROWS = 256 / ncol;
  int oh = blockIdx.y * ROWS + ty;
  int co = blockIdx.x % Cout;
  int b  = blockIdx.x / Cout;
  int ow0 = tx * 4;
  int Cin = C1 + C2;
  long HW = (long)H * W;

  bool mL = (ow0 > 0);
  bool mR = (ow0 + 4 < W);

  float bb = bias[co];
  float acc0 = bb, acc1 = bb, acc2 = bb, acc3 = bb;
  const float* wco = w + (long)co * Cin * 9;

  for (int ci = 0; ci < Cin; ++ci) {
    const float* wp = wco + ci * 9;
    float wv[9];
#pragma unroll
    for (int t = 0; t < 9; ++t) wv[t] = wp[t];
    bool is2b = (ci >= C1) && bcast2;
    const float* plane;
    float bval = 0.f;
    if (ci < C1) plane = in1 + (b * C1 + ci) * HW;
    else if (bcast2) { plane = nullptr; bval = in2[b * C2 + ci - C1]; }
    else plane = in2 + (b * C2 + ci - C1) * HW;

#pragma unroll
    for (int ky = 0; ky < 3; ++ky) {
      int ih = oh + ky - 1;
      bool rv = (unsigned)ih < (unsigned)H;
      float x0, x1, x2, x3, x4, x5;
      if (is2b) {
        x0 = (rv && mL) ? bval : 0.f;
        x1 = rv ? bval : 0.f; x2 = x1; x3 = x1; x4 = x1;
        x5 = (rv && mR) ? bval : 0.f;
      } else {
        const float* row = plane + (long)ih * W + ow0 - 1;
        x0 = (rv && mL) ? row[0] : 0.f;
        x1 = rv ? row[1] : 0.f;
        x2 = rv ? row[2] : 0.f;
        x3 = rv ? row[3] : 0.f;
        x4 = rv ? row[4] : 0.f;
        x5 = (rv && mR) ? row[5] : 0.f;
      }
      float w0 = wv[ky * 3 + 0], w1 = wv[ky * 3 + 1], w2 = wv[ky * 3 + 2];
      acc0 += w0 * x0 + w1 * x1 + w2 * x2;
      acc1 += w0 * x1 + w1 * x2 + w2 * x3;
      acc2 += w0 * x2 + w1 * x3 + w2 * x4;
      acc3 += w0 * x3 + w1 * x4 + w2 * x5;
    }
  }
  if (relu) {
    acc0 = fmaxf(acc0, 0.f); acc1 = fmaxf(acc1, 0.f);
    acc2 = fmaxf(acc2, 0.f); acc3 = fmaxf(acc3, 0.f);
  }
  long obase = ((b * Cout + co) * (long)H + oh) * W + ow0;
  if (mix) {
    const float* m1 = in1 + (b * C1 + co) * HW + (long)oh * W + ow0;
    acc0 = 0.99f * m1[0] + 0.01f * acc0;
    acc1 = 0.99f * m1[1] + 0.01f * acc1;
    acc2 = 0.99f * m1[2] + 0.01f * acc2;
    acc3 = 0.99f * m1[3] + 0.01f * acc3;
  }
  out[obase + 0] = acc0; out[obase + 1] = acc1;
  out[obase + 2] = acc2; out[obase + 3] = acc3;
}

// ================= conv 4x4 s2 p1 + relu, register-tiled =====================
__global__ __launch_bounds__(256) void k_conv4x4s2(
    const float* __restrict__ in, const float* __restrict__ w,
    const float* __restrict__ bias, float* __restrict__ out,
    int B, int Cin, int Hin, int Win, int Cout)
{
  int Ho = Hin >> 1, Wo = Win >> 1;
  int ncol = Wo >> 2;
  int tid = threadIdx.x;
  int tx = tid % ncol, ty = tid / ncol;
  int ROWS = 256 / ncol;
  int oh = blockIdx.y * ROWS + ty;
  int co = blockIdx.x % Cout;
  int b  = blockIdx.x / Cout;
  int ow0 = tx * 4;
  long HWin = (long)Hin * Win;

  int cbase = ow0 * 2 - 1;
  bool mL = (cbase >= 0);
  bool mR = (cbase + 9 < Win);

  float bb = bias[co];
  float acc0 = bb, acc1 = bb, acc2 = bb, acc3 = bb;
  const float* wco = w + (long)co * Cin * 16;

  for (int ci = 0; ci < Cin; ++ci) {
    const float* wp = wco + ci * 16;
    float wv[16];
#pragma unroll
    for (int t = 0; t < 16; ++t) wv[t] = wp[t];
    const float* plane = in + (b * Cin + ci) * HWin;
#pragma unroll
    for (int ky = 0; ky < 4; ++ky) {
      int ih = oh * 2 - 1 + ky;
      bool rv = (unsigned)ih < (unsigned)Hin;
      const float* row = plane + (long)ih * Win + cbase;
      float x[10];
      x[0] = (rv && mL) ? row[0] : 0.f;
#pragma unroll
      for (int i = 1; i < 9; ++i) x[i] = rv ? row[i] : 0.f;
      x[9] = (rv && mR) ? row[9] : 0.f;
      float w0 = wv[ky*4+0], w1 = wv[ky*4+1], w2 = wv[ky*4+2], w3 = wv[ky*4+3];
      acc0 += w0*x[0] + w1*x[1] + w2*x[2] + w3*x[3];
      acc1 += w0*x[2] + w1*x[3] + w2*x[4] + w3*x[5];
      acc2 += w0*x[4] + w1*x[5] + w2*x[6] + w3*x[7];
      acc3 += w0*x[6] + w1*x[7] + w2*x[8] + w3*x[9];
    }
  }
  long obase = ((b * Cout + co) * (long)Ho + oh) * Wo + ow0;
  out[obase + 0] = fmaxf(acc0, 0.f);
  out[obase + 1] = fmaxf(acc1, 0.f);
  out[obase + 2] = fmaxf(acc2, 0.f);
  out[obase + 3] = fmaxf(acc3, 0.f);
}

// ================= convT 4x4 s2 p1 + relu, register-tiled (concat) ==========
// weight layout [Cin, Cout, 4, 4]
__global__ __launch_bounds__(256) void k_convt4x4(
    const float* __restrict__ in1, int C1,
    const float* __restrict__ in2, int C2,
    const float* __restrict__ w, const float* __restrict__ bias,
    float* __restrict__ out, int B, int Hin, int Win, int Cout)
{
  int Ho = Hin * 2, Wo = Win * 2;
  int ncol = Wo >> 2;
  int tid = threadIdx.x;
  int tx = tid % ncol, ty = tid / ncol;
  int ROWS = 256 / ncol;
  int oh = blockIdx.y * ROWS + ty;
  int co = blockIdx.x % Cout;
  int b  = blockIdx.x / Cout;
  int ow0 = tx * 4;
  int Cin = C1 + C2;
  long HWin = (long)Hin * Win;

  int h = ow0 >> 1;          // x[] covers input cols h-1 .. h+2
  bool mL = (h - 1 >= 0);
  bool mR = (h + 2 < Win);
  int g = oh >> 1;
  bool ohodd = oh & 1;
  int ih0 = ohodd ? g : g - 1;   // row0: ky = ohodd?2:3
  int ih1 = ih0 + 1;             // row1: ky = ohodd?0:1
  bool rv0 = ih0 >= 0;
  bool rv1 = ih1 < Hin;

  float bb = bias[co];
  float acc0 = bb, acc1 = bb, acc2 = bb, acc3 = bb;

  for (int ci = 0; ci < Cin; ++ci) {
    const float* plane = (ci < C1) ? (in1 + (b * C1 + ci) * HWin)
                                   : (in2 + (b * C2 + ci - C1) * HWin);
    const float* wp = w + ((long)ci * Cout + co) * 16;
    float wv[16];
#pragma unroll
    for (int t = 0; t < 16; ++t) wv[t] = wp[t];
    float w0[4], w1[4];
#pragma unroll
    for (int t = 0; t < 4; ++t) {
      w0[t] = ohodd ? wv[8 + t] : wv[12 + t];
      w1[t] = ohodd ? wv[t]     : wv[4 + t];
    }
    const float* r0 = plane + (long)ih0 * Win + h - 1;
    const float* r1 = plane + (long)ih1 * Win + h - 1;
    float a0, a1, a2, a3, b0, b1, b2, b3;
    a0 = (rv0 && mL) ? r0[0] : 0.f;
    a1 = rv0 ? r0[1] : 0.f;
    a2 = rv0 ? r0[2] : 0.f;
    a3 = (rv0 && mR) ? r0[3] : 0.f;
    b0 = (rv1 && mL) ? r1[0] : 0.f;
    b1 = rv1 ? r1[1] : 0.f;
    b2 = rv1 ? r1[2] : 0.f;
    b3 = (rv1 && mR) ? r1[3] : 0.f;
    // o=0 (even): kx1 @ x[1], kx3 @ x[0]
    acc0 += w0[1]*a1 + w0[3]*a0 + w1[1]*b1 + w1[3]*b0;
    // o=1 (odd):  kx0 @ x[2], kx2 @ x[1]
    acc1 += w0[0]*a2 + w0[2]*a1 + w1[0]*b2 + w1[2]*b1;
    // o=2 (even): kx1 @ x[2], kx3 @ x[1]
    acc2 += w0[1]*a2 + w0[3]*a1 + w1[1]*b2 + w1[3]*b1;
    // o=3 (odd):  kx0 @ x[3], kx2 @ x[2]
    acc3 += w0[0]*a3 + w0[2]*a2 + w1[0]*b3 + w1[2]*b2;
  }
  long obase = ((b * Cout + co) * (long)Ho + oh) * Wo + ow0;
  out[obase + 0] = fmaxf(acc0, 0.f);
  out[obase + 1] = fmaxf(acc1, 0.f);
  out[obase + 2] = fmaxf(acc2, 0.f);
  out[obase + 3] = fmaxf(acc3, 0.f);
}

// ================= fused q/k projection -> transposed [B][N][8] =============
__global__ __launch_bounds__(256) void k_qkproj(
    const float* __restrict__ x, const float* __restrict__ wq,
    const float* __restrict__ bq, const float* __restrict__ wk,
    const float* __restrict__ bk, float* __restrict__ qT,
    float* __restrict__ kT, int N)
{
  int idx = blockIdx.x * 256 + threadIdx.x;
  int n = idx % N, b = idx / N;
  float qa[8], ka[8];
#pragma unroll
  for (int c = 0; c < 8; ++c) { qa[c] = bq[c]; ka[c] = bk[c]; }
  const float* src = x + (long)b * 64 * N + n;
  for (int ci = 0; ci < 64; ++ci) {
    float xv = src[(long)ci * N];
#pragma unroll
    for (int c = 0; c < 8; ++c) {
      qa[c] += wq[c * 64 + ci] * xv;
      ka[c] += wk[c * 64 + ci] * xv;
    }
  }
  float* qo = qT + ((long)b * N + n) * 8;
  float* ko = kT + ((long)b * N + n) * 8;
#pragma unroll
  for (int c = 0; c < 8; ++c) { qo[c] = qa[c]; ko[c] = ka[c]; }
}

// ================= V projection (1x1, 4-wide float4) ========================
__global__ __launch_bounds__(256) void k_vproj(
    const float* __restrict__ x, const float* __restrict__ w,
    const float* __restrict__ bias, float* __restrict__ v, int N)
{
  int co = blockIdx.x % 64, b = blockIdx.x / 64;
  int n0 = blockIdx.y * 1024 + threadIdx.x * 4;
  float bb = bias[co];
  float a0 = bb, a1 = bb, a2 = bb, a3 = bb;
  const float* src = x + (long)b * 64 * N + n0;
  const float* wp = w + co * 64;
  for (int ci = 0; ci < 64; ++ci) {
    float4 xv = *(const float4*)(src + (long)ci * N);
    float wv = wp[ci];
    a0 += wv * xv.x; a1 += wv * xv.y; a2 += wv * xv.z; a3 += wv * xv.w;
  }
  float4 o; o.x = a0; o.y = a1; o.z = a2; o.w = a3;
  *(float4*)(v + ((long)b * 64 + co) * N + n0) = o;
}

// ================= adaptive avg pool to 8x8 ================================
__global__ __launch_bounds__(256) void k_pool8(
    const float* __restrict__ in, float* __restrict__ out, int B, int C, int H, int W)
{
  int idx = blockIdx.x * 256 + threadIdx.x;
  int total = B * C * 64;
  if (idx >= total) return;
  int ow = idx & 7, oh = (idx >> 3) & 7;
  int c = (idx >> 6) % C, b = idx / (64 * C);
  int bh = H / 8, bw = W / 8;
  const float* src = in + ((long)(b * C + c)) * H * W;
  float s = 0.f;
  for (int y = 0; y < bh; ++y)
    for (int x = 0; x < bw; ++x)
      s += src[(oh * bh + y) * W + ow * bw + x];
  out[idx] = s / (float)(bh * bw);
}

// ================= fc + relu (wave per output) ==============================
__global__ __launch_bounds__(256) void k_fc_relu(
    const float* __restrict__ in, const float* __restrict__ w,
    const float* __restrict__ bias, float* __restrict__ out, int B, int K, int O)
{
  int gi = blockIdx.x * 4 + (threadIdx.x >> 6);
  int lane = threadIdx.x & 63;
  if (gi >= B * O) return;
  int b = gi / O, o = gi % O;
  const float* x = in + (long)b * K;
  const float* wp = w + (long)o * K;
  float s = 0.f;
  for (int i = lane; i < K; i += 64) s += x[i] * wp[i];
#pragma unroll
  for (int d = 1; d < 64; d <<= 1) s += __shfl_xor(s, d);
  if (lane == 0) out[gi] = fmaxf(s + bias[o], 0.f);
}

// ================= line filter: per-row std -> sigmoid mask =================
__global__ __launch_bounds__(256) void k_lf_rowstat(
    const float* __restrict__ x, float* __restrict__ mask_raw, int rows, int W)
{
  int row = blockIdx.x * 4 + (threadIdx.x >> 6);
  int lane = threadIdx.x & 63;
  if (row >= rows) return;
  const float* p = x + (long)row * W;
  float s = 0.f;
  for (int i = lane; i < W; i += 64) s += p[i];
#pragma unroll
  for (int d = 1; d < 64; d <<= 1) s += __shfl_xor(s, d);
  float mean = s / (float)W;
  float v = 0.f;
  for (int i = lane; i < W; i += 64) { float t = p[i] - mean; v += t * t; }
#pragma unroll
  for (int d = 1; d < 64; d <<= 1) v += __shfl_xor(v, d);
  float stdv = sqrtf(v / (float)(W - 1));
  float mask = 1.f / (1.f + __expf(-(0.05f - stdv) * 10.f));
  if (lane == 0) mask_raw[row] = mask;
}

// ================= line filter apply (+optional tanh) =======================
__global__ __launch_bounds__(256) void k_lf_apply(
    const float* __restrict__ x, const float* __restrict__ mask_raw,
    float* __restrict__ out, int BC, int H, int W, float strength, int do_tanh)
{
  long idx = (long)blockIdx.x * 256 + threadIdx.x;
  long total = (long)BC * H * W;
  if (idx >= total) return;
  int wcol = (int)(idx % W);
  int h = (int)((idx / W) % H);
  int bc = (int)(idx / ((long)W * H));
  const float* px = x + (long)bc * H * W;
  const float* pm = mask_raw + (long)bc * H;
  float vs = 0.f, mb = 0.f;
#pragma unroll
  for (int d = -2; d <= 2; ++d) {
    int hh = h + d; hh = hh < 0 ? 0 : (hh >= H ? H - 1 : hh);
    vs += px[hh * W + wcol];
    mb += pm[hh];
  }
  vs *= 0.2f; mb *= 0.2f;
  float m = mb * strength;
  float o = x[idx] * (1.f - m) + vs * m;
  if (do_tanh) o = tanhf(o);
  out[idx] = o;
}

// ================= fused self-attention (4 query rows / block) ==============
#define ATT_TN 4
__global__ __launch_bounds__(256) void k_attn(
    const float* __restrict__ qT, const float* __restrict__ kT,
    const float* __restrict__ vb, const float* __restrict__ xb,
    const float* __restrict__ gamma_p, float* __restrict__ outb, int N)
{
  __shared__ float e[ATT_TN][4096];
  __shared__ float wred[ATT_TN][4];
  __shared__ float rowm[ATT_TN];
  __shared__ float rows_[ATT_TN];
  __shared__ float pvred[4][64][ATT_TN];

  int tid = threadIdx.x;
  int lane = tid & 63, wid = tid >> 6;
  int nb = N / ATT_TN;
  int b = blockIdx.x / nb;
  int n0 = (blockIdx.x % nb) * ATT_TN;

  // q for the 4 rows: uniform (scalar) loads
  float qr[ATT_TN][8];
#pragma unroll
  for (int r = 0; r < ATT_TN; ++r) {
    const float* qp = qT + ((long)b * N + n0 + r) * 8;
#pragma unroll
    for (int c = 0; c < 8; ++c) qr[r][c] = qp[c];
  }

  float lmax[ATT_TN];
#pragma unroll
  for (int r = 0; r < ATT_TN; ++r) lmax[r] = -1e30f;
  for (int j = 0; j < 16; ++j) {
    int m = j * 256 + tid;
    const float* kp = kT + ((long)b * N + m) * 8;
    float4 k0 = *(const float4*)kp;
    float4 k1 = *(const float4*)(kp + 4);
#pragma unroll
    for (int r = 0; r < ATT_TN; ++r) {
      float s = qr[r][0]*k0.x + qr[r][1]*k0.y + qr[r][2]*k0.z + qr[r][3]*k0.w
              + qr[r][4]*k1.x + qr[r][5]*k1.y + qr[r][6]*k1.z + qr[r][7]*k1.w;
      e[r][m] = s;
      lmax[r] = fmaxf(lmax[r], s);
    }
  }
#pragma unroll
  for (int r = 0; r < ATT_TN; ++r)
#pragma unroll
    for (int d = 1; d < 64; d <<= 1) lmax[r] = fmaxf(lmax[r], __shfl_xor(lmax[r], d));
  if (lane == 0)
    for (int r = 0; r < ATT_TN; ++r) wred[r][wid] = lmax[r];
  __syncthreads();
  if (tid < ATT_TN) {
    float m = wred[tid][0];
    for (int w2 = 1; w2 < 4; ++w2) m = fmaxf(m, wred[tid][w2]);
    rowm[tid] = m;
  }
  __syncthreads();
  float rm[ATT_TN];
#pragma unroll
  for (int r = 0; r < ATT_TN; ++r) rm[r] = rowm[r];

  float lsum[ATT_TN] = {0.f, 0.f, 0.f, 0.f};
  for (int j = 0; j < 16; ++j) {
    int m = j * 256 + tid;
#pragma unroll
    for (int r = 0; r < ATT_TN; ++r) {
      float p = __expf(e[r][m] - rm[r]);
      e[r][m] = p;
      lsum[r] += p;
    }
  }
#pragma unroll
  for (int r = 0; r < ATT_TN; ++r)
#pragma unroll
    for (int d = 1; d < 64; d <<= 1) lsum[r] += __shfl_xor(lsum[r], d);
  if (lane == 0)
    for (int r = 0; r < ATT_TN; ++r) wred[r][wid] = lsum[r];
  __syncthreads();
  if (tid < ATT_TN)
    rows_[tid] = wred[tid][0] + wred[tid][1] + wred[tid][2] + wred[tid][3];
  __syncthreads();

  // PV: thread (qq, c); V as float4, e as wave-uniform b128 broadcast
  int c = tid & 63, qq = tid >> 6;
  float acc[ATT_TN] = {0.f, 0.f, 0.f, 0.f};
  const float4* vrow = (const float4*)(vb + ((long)b * 64 + c) * N + qq * (N / 4));
  const int MM = N / 16;  // float4 chunks per quarter
  for (int mm = 0; mm < MM; ++mm) {
    float4 vv = vrow[mm];
    int m = qq * (N / 4) + mm * 4;
#pragma unroll
    for (int r = 0; r < ATT_TN; ++r) {
      float4 ee = *(const float4*)&e[r][m];
      acc[r] += ee.x * vv.x + ee.y * vv.y + ee.z * vv.z + ee.w * vv.w;
    }
  }
#pragma unroll
  for (int r = 0; r < ATT_TN; ++r) pvred[qq][c][r] = acc[r];
  __syncthreads();
  if (tid < 64) {
    float g = gamma_p[0];
#pragma unroll
    for (int r = 0; r < ATT_TN; ++r) {
      float s = pvred[0][tid][r] + pvred[1][tid][r] + pvred[2][tid][r] + pvred[3][tid][r];
      long o = ((long)b * 64 + tid) * N + n0 + r;
      outb[o] = g * (s / rows_[r]) + xb[o];
    }
  }
}

// ---------------- launch ----------------
static inline unsigned gdiv(long total) { return (unsigned)((total + 255) / 256); }

extern "C" void kernel_launch(void* const* d_in, const int* in_sizes, int n_in,
                              void* d_out, int out_size, void* d_ws, size_t ws_size,
                              hipStream_t stream)
{
  (void)in_sizes; (void)n_in; (void)out_size; (void)ws_size;
  const float* sketch   = (const float*)d_in[0];
  const float* depth    = (const float*)d_in[1];
  const float* style    = (const float*)d_in[2];
  const float* enc1_w   = (const float*)d_in[3];
  const float* enc1_b   = (const float*)d_in[4];
  const float* enc2_w   = (const float*)d_in[5];
  const float* enc2_b   = (const float*)d_in[6];
  const float* enc3_w   = (const float*)d_in[7];
  const float* enc3_b   = (const float*)d_in[8];
  const float* se1_w    = (const float*)d_in[9];
  const float* se1_b    = (const float*)d_in[10];
  const float* se2_w    = (const float*)d_in[11];
  const float* se2_b    = (const float*)d_in[12];
  const float* se3_w    = (const float*)d_in[13];
  const float* se3_b    = (const float*)d_in[14];
  const float* sp1_w    = (const float*)d_in[15];
  const float* sp1_b    = (const float*)d_in[16];
  const float* sp2_w    = (const float*)d_in[17];
  const float* sp2_b    = (const float*)d_in[18];
  const float* sm_w     = (const float*)d_in[19];
  const float* sm_b     = (const float*)d_in[20];
  const float* attn_q_w = (const float*)d_in[21];
  const float* attn_q_b = (const float*)d_in[22];
  const float* attn_k_w = (const float*)d_in[23];
  const float* attn_k_b = (const float*)d_in[24];
  const float* attn_v_w = (const float*)d_in[25];
  const float* attn_v_b = (const float*)d_in[26];
  const float* attn_g   = (const float*)d_in[27];
  const float* bn_w     = (const float*)d_in[28];
  const float* bn_b     = (const float*)d_in[29];
  const float* dec3_w   = (const float*)d_in[30];
  const float* dec3_b   = (const float*)d_in[31];
  const float* dec2_w   = (const float*)d_in[32];
  const float* dec2_b   = (const float*)d_in[33];
  const float* dec1_w   = (const float*)d_in[34];
  const float* dec1_b   = (const float*)d_in[35];
  float* out = (float*)d_out;

  float* ws    = (float*)d_ws;
  float* e1    = ws + OFF_E1;
  float* e2    = ws + OFF_E2;
  float* e3a   = ws + OFF_E3A;
  float* e3b   = ws + OFF_E3B;
  float* big16 = ws + OFF_BIG16;
  float* big8  = ws + OFF_BIG8;
  float* b4    = ws + OFF_B4;
  float* vbuf  = ws + OFF_V;
  float* qbuf  = ws + OFF_Q;
  float* kbuf  = ws + OFF_K;
  float* pool  = ws + OFF_POOL;
  float* sf1   = ws + OFF_SF1;
  float* sf2   = ws + OFF_SF2;
  float* rowst = ws + OFF_ROW;
  float* d2lf  = ws + OFF_D2LF;
  float* pre   = ws + OFF_PRE;

  const int B = 4;

  // ---- encoder ----
  // enc1: 256x256, Cin=2 -> 16
  k_conv3x3<<<dim3(B*16, 64), 256, 0, stream>>>(
      sketch, 1, depth, 1, 0, enc1_w, enc1_b, e1, B, 256, 256, 16, 1, 0);
  // enc2: 256->128, 16->32
  k_conv4x4s2<<<dim3(B*32, 16), 256, 0, stream>>>(e1, enc2_w, enc2_b, e2, B, 16, 256, 256, 32);
  // enc3: 128->64, 32->64
  k_conv4x4s2<<<dim3(B*64, 4), 256, 0, stream>>>(e2, enc3_w, enc3_b, e3a, B, 32, 128, 128, 64);
  // line_filter(e3, 0.8): e3a -> e3b
  k_lf_rowstat<<<(B*64*64 + 3)/4, 256, 0, stream>>>(e3a, rowst, B*64*64, 64);
  k_lf_apply<<<gdiv((long)B*64*64*64), 256, 0, stream>>>(e3a, rowst, e3b, B*64, 64, 64, 0.8f, 0);

  // ---- style branch ----
  k_conv3x3<<<dim3(B*16, 64), 256, 0, stream>>>(
      style, 3, nullptr, 0, 0, se1_w, se1_b, big16, B, 256, 256, 16, 1, 0);
  k_conv4x4s2<<<dim3(B*32, 16), 256, 0, stream>>>(big16, se2_w, se2_b, big8, B, 16, 256, 256, 32);
  k_conv4x4s2<<<dim3(B*64, 4), 256, 0, stream>>>(big8, se3_w, se3_b, b4, B, 32, 128, 128, 64);
  k_pool8<<<gdiv(B*64*64), 256, 0, stream>>>(b4, pool, B, 64, 64, 64);
  k_fc_relu<<<(B*64 + 3)/4, 256, 0, stream>>>(pool, sp1_w, sp1_b, sf1, B, 4096, 64);
  k_fc_relu<<<(B*64 + 3)/4, 256, 0, stream>>>(sf1, sp2_w, sp2_b, sf2, B, 64, 64);

  // ---- style merge + mix fused: e3a = 0.99*e3b + 0.01*relu(conv(concat)) ----
  k_conv3x3<<<dim3(B*64, 4), 256, 0, stream>>>(
      e3b, 64, sf2, 64, 1, sm_w, sm_b, e3a, B, 64, 64, 64, 1, 1);

  // ---- self-attention on e3a -> e3b ----
  k_qkproj<<<64, 256, 0, stream>>>(e3a, attn_q_w, attn_q_b, attn_k_w, attn_k_b, qbuf, kbuf, 4096);
  k_vproj<<<dim3(B*64, 4), 256, 0, stream>>>(e3a, attn_v_w, attn_v_b, vbuf, 4096);
  k_attn<<<B * (4096 / ATT_TN), 256, 0, stream>>>(qbuf, kbuf, vbuf, e3a, attn_g, e3b, 4096);

  // ---- bottleneck + decoder ----
  k_conv3x3<<<dim3(B*64, 4), 256, 0, stream>>>(
      e3b, 64, nullptr, 0, 0, bn_w, bn_b, b4, B, 64, 64, 64, 1, 0);
  k_convt4x4<<<dim3(B*32, 16), 256, 0, stream>>>(b4, 64, e3b, 64, dec3_w, dec3_b, big8, B, 64, 64, 32);
  k_convt4x4<<<dim3(B*16, 64), 256, 0, stream>>>(big8, 32, e2, 32, dec2_w, dec2_b, big16, B, 128, 128, 16);
  // line_filter(d2, 0.8): big16 -> d2lf
  k_lf_rowstat<<<(B*16*256 + 3)/4, 256, 0, stream>>>(big16, rowst, B*16*256, 256);
  k_lf_apply<<<gdiv((long)B*16*256*256), 256, 0, stream>>>(big16, rowst, d2lf, B*16, 256, 256, 0.8f, 0);
  // dec1: conv3x3(concat(d2lf, e1)) -> pre (no relu)
  k_conv3x3<<<dim3(B*3, 64), 256, 0, stream>>>(
      d2lf, 16, e1, 16, 0, dec1_w, dec1_b, pre, B, 256, 256, 3, 0, 0);
  // final: tanh(line_filter(pre, 0.9)) -> out
  k_lf_rowstat<<<(B*3*256 + 3)/4, 256, 0, stream>>>(pre, rowst, B*3*256, 256);
  k_lf_apply<<<gdiv((long)B*3*256*256), 256, 0, stream>>>(pre, rowst, out, B*3, 256, 256, 0.9f, 1);
}

// Round 3
// 1611.489 us; speedup vs baseline: 2.4816x; 2.4816x over previous
//
#include <hip/hip_runtime.h>
#include <cstdint>
#include <cstddef>

// ---------------- workspace layout (floats) ----------------
static const size_t OFF_E1    = 0;         // [4,16,256,256]
static const size_t OFF_E2    = 4194304;   // [4,32,128,128]
static const size_t OFF_E3A   = 6291456;   // [4,64,64,64]
static const size_t OFF_E3B   = 7340032;   // [4,64,64,64]
static const size_t OFF_BIG16 = 8388608;   // s1 then d2raw
static const size_t OFF_BIG8  = 12582912;  // s2 then d3
static const size_t OFF_B4    = 14680064;  // s3 then bn-out
static const size_t OFF_V     = 15728640;  // [4,64,4096]
static const size_t OFF_Q     = 16777216;  // [4,4096,8] transposed
static const size_t OFF_K     = 16908288;  // [4,4096,8] transposed
static const size_t OFF_POOL  = 17039360;  // pool then wsum[4][64][9]
static const size_t OFF_SF1   = 17055744;
static const size_t OFF_SF2   = 17056000;
static const size_t OFF_ROW   = 17056256;
static const size_t OFF_D2LF  = 17072640;  // [4,16,256,256]
static const size_t OFF_PRE   = 21266944;  // [4,3,256,256]

// ============== conv3x3 s1 p1, LDS-staged, multi-co per thread ==============
// block: 256 threads = W x ROWS pixels; grid (H/ROWS, B, COUT/CO_T).
// in1: C1 planes; in2: C2 planes (BCAST2: spatially-constant values in2[b*C2+c]).
// CIN_W: channel stride in weight tensor (may exceed C1+C2 when WSUM covers rest).
// WSUM: add precomputed broadcast-channel contribution wsum[b][co][9] w/ edge masks.
// MIX: out = 0.99*in1[co-plane] + 0.01*result (requires C1==COUT).
template<int C1, int C2, int BCAST2, int CIN_W, int W, int H, int ROWS,
         int CI_CH, int COUT, int CO_T, int RELU, int MIX, int WSUM>
__global__ __launch_bounds__(256) void k_c3(
    const float* __restrict__ in1, const float* __restrict__ in2,
    const float* __restrict__ w, const float* __restrict__ bias,
    const float* __restrict__ wsum, float* __restrict__ out)
{
  constexpr int CIN = C1 + C2;
  constexpr int PW = W + 4;
  constexpr int LR = ROWS + 2;
  __shared__ float lds[CI_CH * LR * PW];

  int tid = threadIdx.x;
  int tx = tid % W, ty = tid / W;
  int b = blockIdx.y;
  int co0 = blockIdx.z * CO_T;
  int oh0 = blockIdx.x * ROWS;
  int oh = oh0 + ty;

  float acc[CO_T];
#pragma unroll
  for (int i = 0; i < CO_T; ++i) acc[i] = bias[co0 + i];

  if (WSUM) {
    bool rv0 = oh - 1 >= 0, rv2 = oh + 1 < H;
    bool cv0 = tx - 1 >= 0, cv2 = tx + 1 < W;
    bool rv[3] = {rv0, true, rv2};
    bool cv[3] = {cv0, true, cv2};
    const float* wsp = wsum + ((long)b * COUT + co0) * 9;
#pragma unroll
    for (int co = 0; co < CO_T; ++co)
#pragma unroll
      for (int ky = 0; ky < 3; ++ky)
#pragma unroll
        for (int kx = 0; kx < 3; ++kx)
          acc[co] += (rv[ky] && cv[kx]) ? wsp[co * 9 + ky * 3 + kx] : 0.f;
  }

  for (int c0 = 0; c0 < CIN; c0 += CI_CH) {
    // ---- stage chunk ----
    constexpr int TOTAL = CI_CH * LR * PW;
    for (int i = tid; i < TOTAL; i += 256) {
      int ci_l = i / (LR * PW);
      int rem = i % (LR * PW);
      int r = rem / PW, c = rem % PW;
      int ih = oh0 - 1 + r, iw = c - 1;
      int ci = c0 + ci_l;
      float v = 0.f;
      if ((unsigned)ih < (unsigned)H && (unsigned)iw < (unsigned)W) {
        if (ci < C1) v = in1[((long)(b * C1 + ci) * H + ih) * W + iw];
        else if (BCAST2) v = in2[b * C2 + ci - C1];
        else v = in2[((long)(b * C2 + ci - C1) * H + ih) * W + iw];
      }
      lds[i] = v;
    }
    __syncthreads();
    // ---- accumulate ----
#pragma unroll
    for (int ci_l = 0; ci_l < CI_CH; ++ci_l) {
      int ci = c0 + ci_l;
      float x[3][3];
#pragma unroll
      for (int ky = 0; ky < 3; ++ky)
#pragma unroll
        for (int kx = 0; kx < 3; ++kx)
          x[ky][kx] = lds[ci_l * (LR * PW) + (ty + ky) * PW + tx + kx];
      const float* wb = w + (long)ci * 9;
#pragma unroll
      for (int co = 0; co < CO_T; ++co) {
        const float* wp = wb + (long)(co0 + co) * CIN_W * 9;
#pragma unroll
        for (int ky = 0; ky < 3; ++ky)
#pragma unroll
          for (int kx = 0; kx < 3; ++kx)
            acc[co] += wp[ky * 3 + kx] * x[ky][kx];
      }
    }
    __syncthreads();
  }

#pragma unroll
  for (int co = 0; co < CO_T; ++co) {
    float a = acc[co];
    if (RELU) a = fmaxf(a, 0.f);
    if (MIX) {
      float m = in1[((long)(b * C1 + co0 + co) * H + oh) * W + tx];
      a = 0.99f * m + 0.01f * a;
    }
    out[((long)(b * COUT + co0 + co) * H + oh) * W + tx] = a;
  }
}

// ============== conv4x4 s2 p1 + relu, LDS-staged =============================
// block: 256 threads = TW x TH output pixels (TW == Wout); grid (Ho/TH, B, COUT/CO_T).
template<int CIN, int CI_CH, int COUT, int CO_T, int WIN, int HIN, int TW, int TH>
__global__ __launch_bounds__(256) void k_c4(
    const float* __restrict__ in, const float* __restrict__ w,
    const float* __restrict__ bias, float* __restrict__ out)
{
  constexpr int Wo = WIN / 2, Ho = HIN / 2;
  constexpr int PW = 2 * TW + 4;
  constexpr int LR = 2 * TH + 2;
  __shared__ float lds[CI_CH * LR * PW];

  int tid = threadIdx.x;
  int tx = tid % TW, ty = tid / TW;
  int b = blockIdx.y;
  int co0 = blockIdx.z * CO_T;
  int oh0 = blockIdx.x * TH;
  int oh = oh0 + ty;
  int R0 = 2 * oh0 - 1;

  float acc[CO_T];
#pragma unroll
  for (int i = 0; i < CO_T; ++i) acc[i] = bias[co0 + i];

  for (int c0 = 0; c0 < CIN; c0 += CI_CH) {
    constexpr int TOTAL = CI_CH * LR * PW;
    for (int i = tid; i < TOTAL; i += 256) {
      int ci_l = i / (LR * PW);
      int rem = i % (LR * PW);
      int r = rem / PW, c = rem % PW;
      int ih = R0 + r, iw = c - 1;
      float v = 0.f;
      if ((unsigned)ih < (unsigned)HIN && (unsigned)iw < (unsigned)WIN)
        v = in[((long)(b * CIN + c0 + ci_l) * HIN + ih) * WIN + iw];
      lds[i] = v;
    }
    __syncthreads();
#pragma unroll
    for (int ci_l = 0; ci_l < CI_CH; ++ci_l) {
      int ci = c0 + ci_l;
      float x[4][4];
#pragma unroll
      for (int ky = 0; ky < 4; ++ky)
#pragma unroll
        for (int kx = 0; kx < 4; ++kx)
          x[ky][kx] = lds[ci_l * (LR * PW) + (2 * ty + ky) * PW + 2 * tx + kx];
      const float* wb = w + (long)ci * 16;
#pragma unroll
      for (int co = 0; co < CO_T; ++co) {
        const float* wp = wb + (long)(co0 + co) * CIN * 16;
#pragma unroll
        for (int ky = 0; ky < 4; ++ky)
#pragma unroll
          for (int kx = 0; kx < 4; ++kx)
            acc[co] += wp[ky * 4 + kx] * x[ky][kx];
      }
    }
    __syncthreads();
  }

#pragma unroll
  for (int co = 0; co < CO_T; ++co)
    out[((long)(b * COUT + co0 + co) * Ho + oh) * Wo + tx] = fmaxf(acc[co], 0.f);
}

// ============== convT 4x4 s2 p1 + relu, LDS-staged, 2x2 outputs/thread ======
// weight [Cin][Cout][4][4]. block: 256 thr = TPR row-pairs x WIN col-pairs.
// grid (HIN/TPR, B, COUT/CO_T).
template<int C1, int C2, int COUT, int CO_T, int WIN, int HIN, int TPR, int CI_CH>
__global__ __launch_bounds__(256) void k_ct(
    const float* __restrict__ in1, const float* __restrict__ in2,
    const float* __restrict__ w, const float* __restrict__ bias,
    float* __restrict__ out)
{
  constexpr int CIN = C1 + C2;
  constexpr int Wo = 2 * WIN, Ho = 2 * HIN;
  constexpr int PW = WIN + 4;
  constexpr int LR = TPR + 2;
  __shared__ float lds[CI_CH * LR * PW];

  int tid = threadIdx.x;
  int s = tid % WIN, dt = tid / WIN;
  int b = blockIdx.y;
  int co0 = blockIdx.z * CO_T;
  int t0 = blockIdx.x * TPR;
  int t = t0 + dt;

  float aee[CO_T], aeo[CO_T], aoe[CO_T], aoo[CO_T];
#pragma unroll
  for (int i = 0; i < CO_T; ++i) {
    float bb = bias[co0 + i];
    aee[i] = bb; aeo[i] = bb; aoe[i] = bb; aoo[i] = bb;
  }

  for (int c0 = 0; c0 < CIN; c0 += CI_CH) {
    constexpr int TOTAL = CI_CH * LR * PW;
    for (int i = tid; i < TOTAL; i += 256) {
      int ci_l = i / (LR * PW);
      int rem = i % (LR * PW);
      int r = rem / PW, c = rem % PW;
      int ih = t0 - 1 + r, iw = c - 1;
      int ci = c0 + ci_l;
      float v = 0.f;
      if ((unsigned)ih < (unsigned)HIN && (unsigned)iw < (unsigned)WIN) {
        if (ci < C1) v = in1[((long)(b * C1 + ci) * HIN + ih) * WIN + iw];
        else v = in2[((long)(b * C2 + ci - C1) * HIN + ih) * WIN + iw];
      }
      lds[i] = v;
    }
    __syncthreads();
#pragma unroll
    for (int ci_l = 0; ci_l < CI_CH; ++ci_l) {
      int ci = c0 + ci_l;
      float x[3][3];   // rows t-1,t,t+1 ; cols s-1,s,s+1
#pragma unroll
      for (int r = 0; r < 3; ++r)
#pragma unroll
        for (int c = 0; c < 3; ++c)
          x[r][c] = lds[ci_l * (LR * PW) + (dt + r) * PW + s + c];
      const float* wb = w + (long)ci * COUT * 16;
#pragma unroll
      for (int co = 0; co < CO_T; ++co) {
        const float* wp = wb + (long)(co0 + co) * 16;
        float w00 = wp[0],  w01 = wp[1],  w02 = wp[2],  w03 = wp[3];
        float w10 = wp[4],  w11 = wp[5],  w12 = wp[6],  w13 = wp[7];
        float w20 = wp[8],  w21 = wp[9],  w22 = wp[10], w23 = wp[11];
        float w30 = wp[12], w31 = wp[13], w32 = wp[14], w33 = wp[15];
        aee[co] += w11 * x[1][1] + w13 * x[1][0] + w31 * x[0][1] + w33 * x[0][0];
        aeo[co] += w10 * x[1][2] + w12 * x[1][1] + w30 * x[0][2] + w32 * x[0][1];
        aoe[co] += w01 * x[2][1] + w03 * x[2][0] + w21 * x[1][1] + w23 * x[1][0];
        aoo[co] += w00 * x[2][2] + w02 * x[2][1] + w20 * x[1][2] + w22 * x[1][1];
      }
    }
    __syncthreads();
  }

#pragma unroll
  for (int co = 0; co < CO_T; ++co) {
    long base = ((long)(b * COUT + co0 + co) * Ho + 2 * t) * Wo + 2 * s;
    float2 r0; r0.x = fmaxf(aee[co], 0.f); r0.y = fmaxf(aeo[co], 0.f);
    float2 r1; r1.x = fmaxf(aoe[co], 0.f); r1.y = fmaxf(aoo[co], 0.f);
    *(float2*)(out + base) = r0;
    *(float2*)(out + base + Wo) = r1;
  }
}

// ============== wsum precompute for style-merge broadcast channels ==========
// wsum[b][co][tap] = sum_ci sm_w[co][64+ci][tap] * sf[b][ci]
__global__ __launch_bounds__(256) void k_wsum(
    const float* __restrict__ w, const float* __restrict__ sf,
    float* __restrict__ wsum)
{
  int b = blockIdx.x;
  for (int i = threadIdx.x; i < 576; i += 256) {
    int co = i / 9, t = i % 9;
    float s = 0.f;
    for (int ci = 0; ci < 64; ++ci)
      s += w[((long)co * 128 + 64 + ci) * 9 + t] * sf[b * 64 + ci];
    wsum[((long)b * 64 + co) * 9 + t] = s;
  }
}

// ================= fused q/k projection -> transposed [B][N][8] =============
__global__ __launch_bounds__(256) void k_qkproj(
    const float* __restrict__ x, const float* __restrict__ wq,
    const float* __restrict__ bq, const float* __restrict__ wk,
    const float* __restrict__ bk, float* __restrict__ qT,
    float* __restrict__ kT, int N)
{
  int idx = blockIdx.x * 256 + threadIdx.x;
  int n = idx % N, b = idx / N;
  float qa[8], ka[8];
#pragma unroll
  for (int c = 0; c < 8; ++c) { qa[c] = bq[c]; ka[c] = bk[c]; }
  const float* src = x + (long)b * 64 * N + n;
  for (int ci = 0; ci < 64; ++ci) {
    float xv = src[(long)ci * N];
#pragma unroll
    for (int c = 0; c < 8; ++c) {
      qa[c] += wq[c * 64 + ci] * xv;
      ka[c] += wk[c * 64 + ci] * xv;
    }
  }
  float* qo = qT + ((long)b * N + n) * 8;
  float* ko = kT + ((long)b * N + n) * 8;
#pragma unroll
  for (int c = 0; c < 8; ++c) { qo[c] = qa[c]; ko[c] = ka[c]; }
}

// ================= V projection (1x1, float4) ===============================
__global__ __launch_bounds__(256) void k_vproj(
    const float* __restrict__ x, const float* __restrict__ w,
    const float* __restrict__ bias, float* __restrict__ v, int N)
{
  int co = blockIdx.x % 64, b = blockIdx.x / 64;
  int n0 = blockIdx.y * 1024 + threadIdx.x * 4;
  float bb = bias[co];
  float a0 = bb, a1 = bb, a2 = bb, a3 = bb;
  const float* src = x + (long)b * 64 * N + n0;
  const float* wp = w + co * 64;
  for (int ci = 0; ci < 64; ++ci) {
    float4 xv = *(const float4*)(src + (long)ci * N);
    float wv = wp[ci];
    a0 += wv * xv.x; a1 += wv * xv.y; a2 += wv * xv.z; a3 += wv * xv.w;
  }
  float4 o; o.x = a0; o.y = a1; o.z = a2; o.w = a3;
  *(float4*)(v + ((long)b * 64 + co) * N + n0) = o;
}

// ================= adaptive avg pool to 8x8 ================================
__global__ __launch_bounds__(256) void k_pool8(
    const float* __restrict__ in, float* __restrict__ out, int B, int C, int H, int W)
{
  int idx = blockIdx.x * 256 + threadIdx.x;
  int total = B * C * 64;
  if (idx >= total) return;
  int ow = idx & 7, oh = (idx >> 3) & 7;
  int c = (idx >> 6) % C, b = idx / (64 * C);
  int bh = H / 8, bw = W / 8;
  const float* src = in + ((long)(b * C + c)) * H * W;
  float s = 0.f;
  for (int y = 0; y < bh; ++y)
    for (int x = 0; x < bw; ++x)
      s += src[(oh * bh + y) * W + ow * bw + x];
  out[idx] = s / (float)(bh * bw);
}

// ================= fc + relu (wave per output) ==============================
__global__ __launch_bounds__(256) void k_fc_relu(
    const float* __restrict__ in, const float* __restrict__ w,
    const float* __restrict__ bias, float* __restrict__ out, int B, int K, int O)
{
  int gi = blockIdx.x * 4 + (threadIdx.x >> 6);
  int lane = threadIdx.x & 63;
  if (gi >= B * O) return;
  int b = gi / O, o = gi % O;
  const float* x = in + (long)b * K;
  const float* wp = w + (long)o * K;
  float s = 0.f;
  for (int i = lane; i < K; i += 64) s += x[i] * wp[i];
#pragma unroll
  for (int d = 1; d < 64; d <<= 1) s += __shfl_xor(s, d);
  if (lane == 0) out[gi] = fmaxf(s + bias[o], 0.f);
}

// ================= line filter: per-row std -> sigmoid mask =================
__global__ __launch_bounds__(256) void k_lf_rowstat(
    const float* __restrict__ x, float* __restrict__ mask_raw, int rows, int W)
{
  int row = blockIdx.x * 4 + (threadIdx.x >> 6);
  int lane = threadIdx.x & 63;
  if (row >= rows) return;
  const float* p = x + (long)row * W;
  float s = 0.f;
  for (int i = lane; i < W; i += 64) s += p[i];
#pragma unroll
  for (int d = 1; d < 64; d <<= 1) s += __shfl_xor(s, d);
  float mean = s / (float)W;
  float v = 0.f;
  for (int i = lane; i < W; i += 64) { float t = p[i] - mean; v += t * t; }
#pragma unroll
  for (int d = 1; d < 64; d <<= 1) v += __shfl_xor(v, d);
  float stdv = sqrtf(v / (float)(W - 1));
  float mask = 1.f / (1.f + __expf(-(0.05f - stdv) * 10.f));
  if (lane == 0) mask_raw[row] = mask;
}

// ================= line filter apply (+optional tanh) =======================
__global__ __launch_bounds__(256) void k_lf_apply(
    const float* __restrict__ x, const float* __restrict__ mask_raw,
    float* __restrict__ out, int BC, int H, int W, float strength, int do_tanh)
{
  long idx = (long)blockIdx.x * 256 + threadIdx.x;
  long total = (long)BC * H * W;
  if (idx >= total) return;
  int wcol = (int)(idx % W);
  int h = (int)((idx / W) % H);
  int bc = (int)(idx / ((long)W * H));
  const float* px = x + (long)bc * H * W;
  const float* pm = mask_raw + (long)bc * H;
  float vs = 0.f, mb = 0.f;
#pragma unroll
  for (int d = -2; d <= 2; ++d) {
    int hh = h + d; hh = hh < 0 ? 0 : (hh >= H ? H - 1 : hh);
    vs += px[hh * W + wcol];
    mb += pm[hh];
  }
  vs *= 0.2f; mb *= 0.2f;
  float m = mb * strength;
  float o = x[idx] * (1.f - m) + vs * m;
  if (do_tanh) o = tanhf(o);
  out[idx] = o;
}

// ================= fused self-attention (4 query rows / block) ==============
#define ATT_TN 4
__global__ __launch_bounds__(256) void k_attn(
    const float* __restrict__ qT, const float* __restrict__ kT,
    const float* __restrict__ vb, const float* __restrict__ xb,
    const float* __restrict__ gamma_p, float* __restrict__ outb, int N)
{
  __shared__ float e[ATT_TN][4096];
  __shared__ float wred[ATT_TN][4];
  __shared__ float rowm[ATT_TN];
  __shared__ float rows_[ATT_TN];
  __shared__ float pvred[4][64][ATT_TN];

  int tid = threadIdx.x;
  int lane = tid & 63, wid = tid >> 6;
  int nb = N / ATT_TN;
  int b = blockIdx.x / nb;
  int n0 = (blockIdx.x % nb) * ATT_TN;

  float qr[ATT_TN][8];
#pragma unroll
  for (int r = 0; r < ATT_TN; ++r) {
    const float* qp = qT + ((long)b * N + n0 + r) * 8;
#pragma unroll
    for (int c = 0; c < 8; ++c) qr[r][c] = qp[c];
  }

  float lmax[ATT_TN];
#pragma unroll
  for (int r = 0; r < ATT_TN; ++r) lmax[r] = -1e30f;
  for (int j = 0; j < 16; ++j) {
    int m = j * 256 + tid;
    const float* kp = kT + ((long)b * N + m) * 8;
    float4 k0 = *(const float4*)kp;
    float4 k1 = *(const float4*)(kp + 4);
#pragma unroll
    for (int r = 0; r < ATT_TN; ++r) {
      float s = qr[r][0]*k0.x + qr[r][1]*k0.y + qr[r][2]*k0.z + qr[r][3]*k0.w
              + qr[r][4]*k1.x + qr[r][5]*k1.y + qr[r][6]*k1.z + qr[r][7]*k1.w;
      e[r][m] = s;
      lmax[r] = fmaxf(lmax[r], s);
    }
  }
#pragma unroll
  for (int r = 0; r < ATT_TN; ++r)
#pragma unroll
    for (int d = 1; d < 64; d <<= 1) lmax[r] = fmaxf(lmax[r], __shfl_xor(lmax[r], d));
  if (lane == 0)
    for (int r = 0; r < ATT_TN; ++r) wred[r][wid] = lmax[r];
  __syncthreads();
  if (tid < ATT_TN) {
    float m = wred[tid][0];
    for (int w2 = 1; w2 < 4; ++w2) m = fmaxf(m, wred[tid][w2]);
    rowm[tid] = m;
  }
  __syncthreads();
  float rm[ATT_TN];
#pragma unroll
  for (int r = 0; r < ATT_TN; ++r) rm[r] = rowm[r];

  float lsum[ATT_TN] = {0.f, 0.f, 0.f, 0.f};
  for (int j = 0; j < 16; ++j) {
    int m = j * 256 + tid;
#pragma unroll
    for (int r = 0; r < ATT_TN; ++r) {
      float p = __expf(e[r][m] - rm[r]);
      e[r][m] = p;
      lsum[r] += p;
    }
  }
#pragma unroll
  for (int r = 0; r < ATT_TN; ++r)
#pragma unroll
    for (int d = 1; d < 64; d <<= 1) lsum[r] += __shfl_xor(lsum[r], d);
  if (lane == 0)
    for (int r = 0; r < ATT_TN; ++r) wred[r][wid] = lsum[r];
  __syncthreads();
  if (tid < ATT_TN)
    rows_[tid] = wred[tid][0] + wred[tid][1] + wred[tid][2] + wred[tid][3];
  __syncthreads();

  int c = tid & 63, qq = tid >> 6;
  float acc[ATT_TN] = {0.f, 0.f, 0.f, 0.f};
  const float4* vrow = (const float4*)(vb + ((long)b * 64 + c) * N + qq * (N / 4));
  const int MM = N / 16;
  for (int mm = 0; mm < MM; ++mm) {
    float4 vv = vrow[mm];
    int m = qq * (N / 4) + mm * 4;
#pragma unroll
    for (int r = 0; r < ATT_TN; ++r) {
      float4 ee = *(const float4*)&e[r][m];
      acc[r] += ee.x * vv.x + ee.y * vv.y + ee.z * vv.z + ee.w * vv.w;
    }
  }
#pragma unroll
  for (int r = 0; r < ATT_TN; ++r) pvred[qq][c][r] = acc[r];
  __syncthreads();
  if (tid < 64) {
    float g = gamma_p[0];
#pragma unroll
    for (int r = 0; r < ATT_TN; ++r) {
      float s = pvred[0][tid][r] + pvred[1][tid][r] + pvred[2][tid][r] + pvred[3][tid][r];
      long o = ((long)b * 64 + tid) * N + n0 + r;
      outb[o] = g * (s / rows_[r]) + xb[o];
    }
  }
}

// ---------------- launch ----------------
static inline unsigned gdiv(long total) { return (unsigned)((total + 255) / 256); }

extern "C" void kernel_launch(void* const* d_in, const int* in_sizes, int n_in,
                              void* d_out, int out_size, void* d_ws, size_t ws_size,
                              hipStream_t stream)
{
  (void)in_sizes; (void)n_in; (void)out_size; (void)ws_size;
  const float* sketch   = (const float*)d_in[0];
  const float* depth    = (const float*)d_in[1];
  const float* style    = (const float*)d_in[2];
  const float* enc1_w   = (const float*)d_in[3];
  const float* enc1_b   = (const float*)d_in[4];
  const float* enc2_w   = (const float*)d_in[5];
  const float* enc2_b   = (const float*)d_in[6];
  const float* enc3_w   = (const float*)d_in[7];
  const float* enc3_b   = (const float*)d_in[8];
  const float* se1_w    = (const float*)d_in[9];
  const float* se1_b    = (const float*)d_in[10];
  const float* se2_w    = (const float*)d_in[11];
  const float* se2_b    = (const float*)d_in[12];
  const float* se3_w    = (const float*)d_in[13];
  const float* se3_b    = (const float*)d_in[14];
  const float* sp1_w    = (const float*)d_in[15];
  const float* sp1_b    = (const float*)d_in[16];
  const float* sp2_w    = (const float*)d_in[17];
  const float* sp2_b    = (const float*)d_in[18];
  const float* sm_w     = (const float*)d_in[19];
  const float* sm_b     = (const float*)d_in[20];
  const float* attn_q_w = (const float*)d_in[21];
  const float* attn_q_b = (const float*)d_in[22];
  const float* attn_k_w = (const float*)d_in[23];
  const float* attn_k_b = (const float*)d_in[24];
  const float* attn_v_w = (const float*)d_in[25];
  const float* attn_v_b = (const float*)d_in[26];
  const float* attn_g   = (const float*)d_in[27];
  const float* bn_w     = (const float*)d_in[28];
  const float* bn_b     = (const float*)d_in[29];
  const float* dec3_w   = (const float*)d_in[30];
  const float* dec3_b   = (const float*)d_in[31];
  const float* dec2_w   = (const float*)d_in[32];
  const float* dec2_b   = (const float*)d_in[33];
  const float* dec1_w   = (const float*)d_in[34];
  const float* dec1_b   = (const float*)d_in[35];
  float* out = (float*)d_out;

  float* ws    = (float*)d_ws;
  float* e1    = ws + OFF_E1;
  float* e2    = ws + OFF_E2;
  float* e3a   = ws + OFF_E3A;
  float* e3b   = ws + OFF_E3B;
  float* big16 = ws + OFF_BIG16;
  float* big8  = ws + OFF_BIG8;
  float* b4    = ws + OFF_B4;
  float* vbuf  = ws + OFF_V;
  float* qbuf  = ws + OFF_Q;
  float* kbuf  = ws + OFF_K;
  float* pool  = ws + OFF_POOL;   // reused as wsum after fc2
  float* sf1   = ws + OFF_SF1;
  float* sf2   = ws + OFF_SF2;
  float* rowst = ws + OFF_ROW;
  float* d2lf  = ws + OFF_D2LF;
  float* pre   = ws + OFF_PRE;

  const int B = 4;

  // ---- encoder ----
  k_c3<1,1,0, 2, 256,256,1, 2, 16,16, 1,0,0><<<dim3(256, B, 1), 256, 0, stream>>>(
      sketch, depth, enc1_w, enc1_b, nullptr, e1);
  k_c4<16,4,32,16, 256,256, 128,2><<<dim3(64, B, 2), 256, 0, stream>>>(
      e1, enc2_w, enc2_b, e2);
  k_c4<32,4,64,8, 128,128, 64,4><<<dim3(16, B, 8), 256, 0, stream>>>(
      e2, enc3_w, enc3_b, e3a);
  k_lf_rowstat<<<(B*64*64 + 3)/4, 256, 0, stream>>>(e3a, rowst, B*64*64, 64);
  k_lf_apply<<<gdiv((long)B*64*64*64), 256, 0, stream>>>(e3a, rowst, e3b, B*64, 64, 64, 0.8f, 0);

  // ---- style branch ----
  k_c3<3,0,0, 3, 256,256,1, 3, 16,16, 1,0,0><<<dim3(256, B, 1), 256, 0, stream>>>(
      style, nullptr, se1_w, se1_b, nullptr, big16);
  k_c4<16,4,32,16, 256,256, 128,2><<<dim3(64, B, 2), 256, 0, stream>>>(
      big16, se2_w, se2_b, big8);
  k_c4<32,4,64,8, 128,128, 64,4><<<dim3(16, B, 8), 256, 0, stream>>>(
      big8, se3_w, se3_b, b4);
  k_pool8<<<gdiv(B*64*64), 256, 0, stream>>>(b4, pool, B, 64, 64, 64);
  k_fc_relu<<<(B*64 + 3)/4, 256, 0, stream>>>(pool, sp1_w, sp1_b, sf1, B, 4096, 64);
  k_fc_relu<<<(B*64 + 3)/4, 256, 0, stream>>>(sf1, sp2_w, sp2_b, sf2, B, 64, 64);

  // ---- style merge (+mix fused, bcast channels via wsum) ----
  k_wsum<<<B, 256, 0, stream>>>(sm_w, sf2, pool);
  k_c3<64,0,0, 128, 64,64,4, 8, 64,8, 1,1,1><<<dim3(16, B, 8), 256, 0, stream>>>(
      e3b, nullptr, sm_w, sm_b, pool, e3a);

  // ---- self-attention on e3a -> e3b ----
  k_qkproj<<<64, 256, 0, stream>>>(e3a, attn_q_w, attn_q_b, attn_k_w, attn_k_b, qbuf, kbuf, 4096);
  k_vproj<<<dim3(B*64, 4), 256, 0, stream>>>(e3a, attn_v_w, attn_v_b, vbuf, 4096);
  k_attn<<<B * (4096 / ATT_TN), 256, 0, stream>>>(qbuf, kbuf, vbuf, e3a, attn_g, e3b, 4096);

  // ---- bottleneck + decoder ----
  k_c3<64,0,0, 64, 64,64,4, 8, 64,8, 1,0,0><<<dim3(16, B, 8), 256, 0, stream>>>(
      e3b, nullptr, bn_w, bn_b, nullptr, b4);
  k_ct<64,64,32,4, 64,64, 4,8><<<dim3(16, B, 8), 256, 0, stream>>>(
      b4, e3b, dec3_w, dec3_b, big8);
  k_ct<32,32,16,8, 128,128, 2,8><<<dim3(64, B, 2), 256, 0, stream>>>(
      big8, e2, dec2_w, dec2_b, big16);
  k_lf_rowstat<<<(B*16*256 + 3)/4, 256, 0, stream>>>(big16, rowst, B*16*256, 256);
  k_lf_apply<<<gdiv((long)B*16*256*256), 256, 0, stream>>>(big16, rowst, d2lf, B*16, 256, 256, 0.8f, 0);
  k_c3<16,16,0, 32, 256,256,1, 8, 3,3, 0,0,0><<<dim3(256, B, 1), 256, 0, stream>>>(
      d2lf, e1, dec1_w, dec1_b, nullptr, pre);
  k_lf_rowstat<<<(B*3*256 + 3)/4, 256, 0, stream>>>(pre, rowst, B*3*256, 256);
  k_lf_apply<<<gdiv((long)B*3*256*256), 256, 0, stream>>>(pre, rowst, out, B*3, 256, 256, 0.9f, 1);
}

// Round 4
// 1403.925 us; speedup vs baseline: 2.8485x; 1.1478x over previous
//
#include <hip/hip_runtime.h>
#include <cstdint>
#include <cstddef>

// ---------------- workspace layout (floats) ----------------
static const size_t OFF_E1    = 0;         // [4,16,256,256]
static const size_t OFF_E2    = 4194304;   // [4,32,128,128]
static const size_t OFF_E3A   = 6291456;   // [4,64,64,64]
static const size_t OFF_E3B   = 7340032;   // [4,64,64,64]
static const size_t OFF_BIG16 = 8388608;   // s1 then d2raw
static const size_t OFF_BIG8  = 12582912;  // s2 then d3
static const size_t OFF_B4    = 14680064;  // s3 then bn-out
static const size_t OFF_V     = 15728640;  // vT [4,4096,64]
static const size_t OFF_Q     = 16777216;  // qT [4,4096,8]
static const size_t OFF_K     = 16908288;  // kC [4,8,4096]
static const size_t OFF_POOL  = 17039360;  // pool then wsum[4][64][9]
static const size_t OFF_SF1   = 17055744;
static const size_t OFF_SF2   = 17056000;
static const size_t OFF_ROW   = 17056256;
static const size_t OFF_D2LF  = 17072640;  // [4,16,256,256]
static const size_t OFF_PRE   = 21266944;  // [4,3,256,256]

// ============== conv3x3 s1 p1, LDS-staged, multi-co per thread ==============
template<int C1, int C2, int BCAST2, int CIN_W, int W, int H, int ROWS,
         int CI_CH, int COUT, int CO_T, int RELU, int MIX, int WSUM>
__global__ __launch_bounds__(256) void k_c3(
    const float* __restrict__ in1, const float* __restrict__ in2,
    const float* __restrict__ w, const float* __restrict__ bias,
    const float* __restrict__ wsum, float* __restrict__ out)
{
  constexpr int CIN = C1 + C2;
  constexpr int PW = W + 4;
  constexpr int LR = ROWS + 2;
  __shared__ float lds[CI_CH * LR * PW];

  int tid = threadIdx.x;
  int tx = tid % W, ty = tid / W;
  int b = blockIdx.y;
  int co0 = blockIdx.z * CO_T;
  int oh0 = blockIdx.x * ROWS;
  int oh = oh0 + ty;

  float acc[CO_T];
#pragma unroll
  for (int i = 0; i < CO_T; ++i) acc[i] = bias[co0 + i];

  if (WSUM) {
    bool rv0 = oh - 1 >= 0, rv2 = oh + 1 < H;
    bool cv0 = tx - 1 >= 0, cv2 = tx + 1 < W;
    bool rv[3] = {rv0, true, rv2};
    bool cv[3] = {cv0, true, cv2};
    const float* wsp = wsum + ((long)b * COUT + co0) * 9;
#pragma unroll
    for (int co = 0; co < CO_T; ++co)
#pragma unroll
      for (int ky = 0; ky < 3; ++ky)
#pragma unroll
        for (int kx = 0; kx < 3; ++kx)
          acc[co] += (rv[ky] && cv[kx]) ? wsp[co * 9 + ky * 3 + kx] : 0.f;
  }

  for (int c0 = 0; c0 < CIN; c0 += CI_CH) {
    constexpr int TOTAL = CI_CH * LR * PW;
    for (int i = tid; i < TOTAL; i += 256) {
      int ci_l = i / (LR * PW);
      int rem = i % (LR * PW);
      int r = rem / PW, c = rem % PW;
      int ih = oh0 - 1 + r, iw = c - 1;
      int ci = c0 + ci_l;
      float v = 0.f;
      if ((unsigned)ih < (unsigned)H && (unsigned)iw < (unsigned)W) {
        if (ci < C1) v = in1[((long)(b * C1 + ci) * H + ih) * W + iw];
        else if (BCAST2) v = in2[b * C2 + ci - C1];
        else v = in2[((long)(b * C2 + ci - C1) * H + ih) * W + iw];
      }
      lds[i] = v;
    }
    __syncthreads();
#pragma unroll
    for (int ci_l = 0; ci_l < CI_CH; ++ci_l) {
      int ci = c0 + ci_l;
      float x[3][3];
#pragma unroll
      for (int ky = 0; ky < 3; ++ky)
#pragma unroll
        for (int kx = 0; kx < 3; ++kx)
          x[ky][kx] = lds[ci_l * (LR * PW) + (ty + ky) * PW + tx + kx];
      const float* wb = w + (long)ci * 9;
#pragma unroll
      for (int co = 0; co < CO_T; ++co) {
        const float* wp = wb + (long)(co0 + co) * CIN_W * 9;
#pragma unroll
        for (int ky = 0; ky < 3; ++ky)
#pragma unroll
          for (int kx = 0; kx < 3; ++kx)
            acc[co] += wp[ky * 3 + kx] * x[ky][kx];
      }
    }
    __syncthreads();
  }

#pragma unroll
  for (int co = 0; co < CO_T; ++co) {
    float a = acc[co];
    if (RELU) a = fmaxf(a, 0.f);
    if (MIX) {
      float m = in1[((long)(b * C1 + co0 + co) * H + oh) * W + tx];
      a = 0.99f * m + 0.01f * a;
    }
    out[((long)(b * COUT + co0 + co) * H + oh) * W + tx] = a;
  }
}

// ============== conv4x4 s2 p1 + relu, LDS-staged =============================
template<int CIN, int CI_CH, int COUT, int CO_T, int WIN, int HIN, int TW, int TH>
__global__ __launch_bounds__(256) void k_c4(
    const float* __restrict__ in, const float* __restrict__ w,
    const float* __restrict__ bias, float* __restrict__ out)
{
  constexpr int Wo = WIN / 2, Ho = HIN / 2;
  constexpr int PW = 2 * TW + 4;
  constexpr int LR = 2 * TH + 2;
  __shared__ float lds[CI_CH * LR * PW];

  int tid = threadIdx.x;
  int tx = tid % TW, ty = tid / TW;
  int b = blockIdx.y;
  int co0 = blockIdx.z * CO_T;
  int oh0 = blockIdx.x * TH;
  int oh = oh0 + ty;
  int R0 = 2 * oh0 - 1;

  float acc[CO_T];
#pragma unroll
  for (int i = 0; i < CO_T; ++i) acc[i] = bias[co0 + i];

  for (int c0 = 0; c0 < CIN; c0 += CI_CH) {
    constexpr int TOTAL = CI_CH * LR * PW;
    for (int i = tid; i < TOTAL; i += 256) {
      int ci_l = i / (LR * PW);
      int rem = i % (LR * PW);
      int r = rem / PW, c = rem % PW;
      int ih = R0 + r, iw = c - 1;
      float v = 0.f;
      if ((unsigned)ih < (unsigned)HIN && (unsigned)iw < (unsigned)WIN)
        v = in[((long)(b * CIN + c0 + ci_l) * HIN + ih) * WIN + iw];
      lds[i] = v;
    }
    __syncthreads();
#pragma unroll
    for (int ci_l = 0; ci_l < CI_CH; ++ci_l) {
      int ci = c0 + ci_l;
      float x[4][4];
#pragma unroll
      for (int ky = 0; ky < 4; ++ky)
#pragma unroll
        for (int kx = 0; kx < 4; ++kx)
          x[ky][kx] = lds[ci_l * (LR * PW) + (2 * ty + ky) * PW + 2 * tx + kx];
      const float* wb = w + (long)ci * 16;
#pragma unroll
      for (int co = 0; co < CO_T; ++co) {
        const float* wp = wb + (long)(co0 + co) * CIN * 16;
#pragma unroll
        for (int ky = 0; ky < 4; ++ky)
#pragma unroll
          for (int kx = 0; kx < 4; ++kx)
            acc[co] += wp[ky * 4 + kx] * x[ky][kx];
      }
    }
    __syncthreads();
  }

#pragma unroll
  for (int co = 0; co < CO_T; ++co)
    out[((long)(b * COUT + co0 + co) * Ho + oh) * Wo + tx] = fmaxf(acc[co], 0.f);
}

// ============== convT 4x4 s2 p1 + relu, LDS-staged, 2x2 outputs/thread ======
template<int C1, int C2, int COUT, int CO_T, int WIN, int HIN, int TPR, int CI_CH>
__global__ __launch_bounds__(256) void k_ct(
    const float* __restrict__ in1, const float* __restrict__ in2,
    const float* __restrict__ w, const float* __restrict__ bias,
    float* __restrict__ out)
{
  constexpr int CIN = C1 + C2;
  constexpr int Wo = 2 * WIN, Ho = 2 * HIN;
  constexpr int PW = WIN + 4;
  constexpr int LR = TPR + 2;
  __shared__ float lds[CI_CH * LR * PW];

  int tid = threadIdx.x;
  int s = tid % WIN, dt = tid / WIN;
  int b = blockIdx.y;
  int co0 = blockIdx.z * CO_T;
  int t0 = blockIdx.x * TPR;
  int t = t0 + dt;

  float aee[CO_T], aeo[CO_T], aoe[CO_T], aoo[CO_T];
#pragma unroll
  for (int i = 0; i < CO_T; ++i) {
    float bb = bias[co0 + i];
    aee[i] = bb; aeo[i] = bb; aoe[i] = bb; aoo[i] = bb;
  }

  for (int c0 = 0; c0 < CIN; c0 += CI_CH) {
    constexpr int TOTAL = CI_CH * LR * PW;
    for (int i = tid; i < TOTAL; i += 256) {
      int ci_l = i / (LR * PW);
      int rem = i % (LR * PW);
      int r = rem / PW, c = rem % PW;
      int ih = t0 - 1 + r, iw = c - 1;
      int ci = c0 + ci_l;
      float v = 0.f;
      if ((unsigned)ih < (unsigned)HIN && (unsigned)iw < (unsigned)WIN) {
        if (ci < C1) v = in1[((long)(b * C1 + ci) * HIN + ih) * WIN + iw];
        else v = in2[((long)(b * C2 + ci - C1) * HIN + ih) * WIN + iw];
      }
      lds[i] = v;
    }
    __syncthreads();
#pragma unroll
    for (int ci_l = 0; ci_l < CI_CH; ++ci_l) {
      int ci = c0 + ci_l;
      float x[3][3];
#pragma unroll
      for (int r = 0; r < 3; ++r)
#pragma unroll
        for (int c = 0; c < 3; ++c)
          x[r][c] = lds[ci_l * (LR * PW) + (dt + r) * PW + s + c];
      const float* wb = w + (long)ci * COUT * 16;
#pragma unroll
      for (int co = 0; co < CO_T; ++co) {
        const float* wp = wb + (long)(co0 + co) * 16;
        float w00 = wp[0],  w01 = wp[1],  w02 = wp[2],  w03 = wp[3];
        float w10 = wp[4],  w11 = wp[5],  w12 = wp[6],  w13 = wp[7];
        float w20 = wp[8],  w21 = wp[9],  w22 = wp[10], w23 = wp[11];
        float w30 = wp[12], w31 = wp[13], w32 = wp[14], w33 = wp[15];
        aee[co] += w11 * x[1][1] + w13 * x[1][0] + w31 * x[0][1] + w33 * x[0][0];
        aeo[co] += w10 * x[1][2] + w12 * x[1][1] + w30 * x[0][2] + w32 * x[0][1];
        aoe[co] += w01 * x[2][1] + w03 * x[2][0] + w21 * x[1][1] + w23 * x[1][0];
        aoo[co] += w00 * x[2][2] + w02 * x[2][1] + w20 * x[1][2] + w22 * x[1][1];
      }
    }
    __syncthreads();
  }

#pragma unroll
  for (int co = 0; co < CO_T; ++co) {
    long base = ((long)(b * COUT + co0 + co) * Ho + 2 * t) * Wo + 2 * s;
    float2 r0; r0.x = fmaxf(aee[co], 0.f); r0.y = fmaxf(aeo[co], 0.f);
    float2 r1; r1.x = fmaxf(aoe[co], 0.f); r1.y = fmaxf(aoo[co], 0.f);
    *(float2*)(out + base) = r0;
    *(float2*)(out + base + Wo) = r1;
  }
}

// ============== wsum precompute for style-merge broadcast channels ==========
__global__ __launch_bounds__(256) void k_wsum(
    const float* __restrict__ w, const float* __restrict__ sf,
    float* __restrict__ wsum)
{
  int b = blockIdx.x;
  for (int i = threadIdx.x; i < 576; i += 256) {
    int co = i / 9, t = i % 9;
    float s = 0.f;
    for (int ci = 0; ci < 64; ++ci)
      s += w[((long)co * 128 + 64 + ci) * 9 + t] * sf[b * 64 + ci];
    wsum[((long)b * 64 + co) * 9 + t] = s;
  }
}

// ============== q/k projection -> qT [B][N][8], kC [B][8][N] ================
__global__ __launch_bounds__(256) void k_qkproj(
    const float* __restrict__ x, const float* __restrict__ wq,
    const float* __restrict__ bq, const float* __restrict__ wk,
    const float* __restrict__ bk, float* __restrict__ qT,
    float* __restrict__ kC, int N)
{
  int idx = blockIdx.x * 256 + threadIdx.x;
  int n = idx % N, b = idx / N;
  float qa[8], ka[8];
#pragma unroll
  for (int c = 0; c < 8; ++c) { qa[c] = bq[c]; ka[c] = bk[c]; }
  const float* src = x + (long)b * 64 * N + n;
  for (int ci = 0; ci < 64; ++ci) {
    float xv = src[(long)ci * N];
#pragma unroll
    for (int c = 0; c < 8; ++c) {
      qa[c] += wq[c * 64 + ci] * xv;
      ka[c] += wk[c * 64 + ci] * xv;
    }
  }
  float* qo = qT + ((long)b * N + n) * 8;
#pragma unroll
  for (int c = 0; c < 8; ++c) qo[c] = qa[c];
#pragma unroll
  for (int c = 0; c < 8; ++c) kC[((long)b * 8 + c) * N + n] = ka[c];
}

// ============== V projection -> vT [B][N][64] ================================
__global__ __launch_bounds__(256) void k_vprojT(
    const float* __restrict__ x, const float* __restrict__ w,
    const float* __restrict__ bias, float* __restrict__ vT, int N)
{
  int idx = blockIdx.x * 256 + threadIdx.x;
  int n = idx % N, b = idx / N;
  float va[64];
#pragma unroll
  for (int c = 0; c < 64; ++c) va[c] = bias[c];
  const float* src = x + (long)b * 64 * N + n;
  for (int ci = 0; ci < 64; ++ci) {
    float xv = src[(long)ci * N];
#pragma unroll
    for (int c = 0; c < 64; ++c) va[c] += w[c * 64 + ci] * xv;
  }
  float* vo = vT + ((long)b * N + n) * 64;
#pragma unroll
  for (int c = 0; c < 64; c += 4) {
    float4 o; o.x = va[c]; o.y = va[c+1]; o.z = va[c+2]; o.w = va[c+3];
    *(float4*)(vo + c) = o;
  }
}

// ============== flash attention, fp32, TQ=16 TK=64 ==========================
// thread (qg = tid>>4, sg = tid&15): q row n0+qg; 4 channels sg*4..+3
__global__ __launch_bounds__(256) void k_fattn(
    const float* __restrict__ qT, const float* __restrict__ kC,
    const float* __restrict__ vT, const float* __restrict__ xb,
    const float* __restrict__ gamma_p, float* __restrict__ outb, int N)
{
  __shared__ float k_s[8][68];
  __shared__ float v_s[64 * 64];   // [m][c]; reused as o_s[64][18] at end
  __shared__ float p_s[16][68];

  int tid = threadIdx.x;
  int b = blockIdx.y;
  int n0 = blockIdx.x * 16;
  int qg = tid >> 4;
  int sg = tid & 15;

  float qv[8];
  {
    const float4* qp = (const float4*)(qT + ((long)b * N + n0 + qg) * 8);
    float4 a = qp[0], c = qp[1];
    qv[0]=a.x; qv[1]=a.y; qv[2]=a.z; qv[3]=a.w;
    qv[4]=c.x; qv[5]=c.y; qv[6]=c.z; qv[7]=c.w;
  }

  float o0=0.f, o1=0.f, o2=0.f, o3=0.f;
  float m_run = -3.0e38f, l_run = 0.f;

  const float* kbase = kC + (long)b * 8 * N;
  const float* vbase = vT + (long)b * N * 64;

  for (int t = 0; t < 64; ++t) {
    int m0 = t * 64;
    // issue V loads to regs (latency hidden under QK)
    float4 vreg0, vreg1, vreg2, vreg3;
    {
      const float4* vp = (const float4*)(vbase + (long)m0 * 64) + tid;
      vreg0 = vp[0]; vreg1 = vp[256]; vreg2 = vp[512]; vreg3 = vp[768];
    }
    // stage K tile [8][64]
    if (tid < 128) {
      int kk = tid >> 4, seg = tid & 15;
      float4 kv4 = *(const float4*)(kbase + (long)kk * N + m0 + seg * 4);
      *(float4*)&k_s[kk][seg * 4] = kv4;
    }
    __syncthreads();
    // QK^T for m = sg*4 .. +3
    float s0=0.f, s1=0.f, s2=0.f, s3=0.f;
#pragma unroll
    for (int kk = 0; kk < 8; ++kk) {
      float4 kx = *(const float4*)&k_s[kk][sg * 4];
      float qk = qv[kk];
      s0 += qk * kx.x; s1 += qk * kx.y; s2 += qk * kx.z; s3 += qk * kx.w;
    }
    // online softmax stats (row = 16 lanes of same qg)
    float tmax = fmaxf(fmaxf(s0, s1), fmaxf(s2, s3));
#pragma unroll
    for (int d = 1; d < 16; d <<= 1) tmax = fmaxf(tmax, __shfl_xor(tmax, d));
    float m_new = fmaxf(m_run, tmax);
    float scale = __expf(m_run - m_new);
    float p0 = __expf(s0 - m_new), p1 = __expf(s1 - m_new);
    float p2 = __expf(s2 - m_new), p3 = __expf(s3 - m_new);
    float tsum = p0 + p1 + p2 + p3;
#pragma unroll
    for (int d = 1; d < 16; d <<= 1) tsum += __shfl_xor(tsum, d);
    l_run = l_run * scale + tsum;
    m_run = m_new;
    o0 *= scale; o1 *= scale; o2 *= scale; o3 *= scale;
    { float4 pw; pw.x=p0; pw.y=p1; pw.z=p2; pw.w=p3;
      *(float4*)&p_s[qg][sg * 4] = pw; }
    // commit V regs to LDS
    {
      float* vd = v_s + tid * 4;
      *(float4*)(vd +    0) = vreg0;
      *(float4*)(vd + 1024) = vreg1;
      *(float4*)(vd + 2048) = vreg2;
      *(float4*)(vd + 3072) = vreg3;
    }
    __syncthreads();
    // PV: o[c] += p[m] * v[m][c]
#pragma unroll 4
    for (int mm = 0; mm < 16; ++mm) {
      float4 pp = *(const float4*)&p_s[qg][mm * 4];
      const float* vr = v_s + (mm * 4) * 64 + sg * 4;
      float4 va = *(const float4*)(vr);
      float4 vb4 = *(const float4*)(vr + 64);
      float4 vc = *(const float4*)(vr + 128);
      float4 vd = *(const float4*)(vr + 192);
      o0 += pp.x*va.x + pp.y*vb4.x + pp.z*vc.x + pp.w*vd.x;
      o1 += pp.x*va.y + pp.y*vb4.y + pp.z*vc.y + pp.w*vd.y;
      o2 += pp.x*va.z + pp.y*vb4.z + pp.z*vc.z + pp.w*vd.z;
      o3 += pp.x*va.w + pp.y*vb4.w + pp.z*vc.w + pp.w*vd.w;
    }
    __syncthreads();
  }
  // normalize, transpose through LDS (v_s reused as o_s[64][18])
  float inv_l = 1.f / l_run;
  v_s[(sg*4+0)*18 + qg] = o0 * inv_l;
  v_s[(sg*4+1)*18 + qg] = o1 * inv_l;
  v_s[(sg*4+2)*18 + qg] = o2 * inv_l;
  v_s[(sg*4+3)*18 + qg] = o3 * inv_l;
  __syncthreads();
  float g = gamma_p[0];
  for (int idx = tid; idx < 1024; idx += 256) {
    int c = idx >> 4, qq = idx & 15;
    long off = ((long)b * 64 + c) * N + n0 + qq;
    outb[off] = g * v_s[c * 18 + qq] + xb[off];
  }
}

// ================= adaptive avg pool to 8x8 ================================
__global__ __launch_bounds__(256) void k_pool8(
    const float* __restrict__ in, float* __restrict__ out, int B, int C, int H, int W)
{
  int idx = blockIdx.x * 256 + threadIdx.x;
  int total = B * C * 64;
  if (idx >= total) return;
  int ow = idx & 7, oh = (idx >> 3) & 7;
  int c = (idx >> 6) % C, b = idx / (64 * C);
  int bh = H / 8, bw = W / 8;
  const float* src = in + ((long)(b * C + c)) * H * W;
  float s = 0.f;
  for (int y = 0; y < bh; ++y)
    for (int x = 0; x < bw; ++x)
      s += src[(oh * bh + y) * W + ow * bw + x];
  out[idx] = s / (float)(bh * bw);
}

// ================= fc + relu (wave per output) ==============================
__global__ __launch_bounds__(256) void k_fc_relu(
    const float* __restrict__ in, const float* __restrict__ w,
    const float* __restrict__ bias, float* __restrict__ out, int B, int K, int O)
{
  int gi = blockIdx.x * 4 + (threadIdx.x >> 6);
  int lane = threadIdx.x & 63;
  if (gi >= B * O) return;
  int b = gi / O, o = gi % O;
  const float* x = in + (long)b * K;
  const float* wp = w + (long)o * K;
  float s = 0.f;
  for (int i = lane; i < K; i += 64) s += x[i] * wp[i];
#pragma unroll
  for (int d = 1; d < 64; d <<= 1) s += __shfl_xor(s, d);
  if (lane == 0) out[gi] = fmaxf(s + bias[o], 0.f);
}

// ================= line filter: per-row std -> sigmoid mask =================
__global__ __launch_bounds__(256) void k_lf_rowstat(
    const float* __restrict__ x, float* __restrict__ mask_raw, int rows, int W)
{
  int row = blockIdx.x * 4 + (threadIdx.x >> 6);
  int lane = threadIdx.x & 63;
  if (row >= rows) return;
  const float* p = x + (long)row * W;
  float s = 0.f;
  for (int i = lane; i < W; i += 64) s += p[i];
#pragma unroll
  for (int d = 1; d < 64; d <<= 1) s += __shfl_xor(s, d);
  float mean = s / (float)W;
  float v = 0.f;
  for (int i = lane; i < W; i += 64) { float t = p[i] - mean; v += t * t; }
#pragma unroll
  for (int d = 1; d < 64; d <<= 1) v += __shfl_xor(v, d);
  float stdv = sqrtf(v / (float)(W - 1));
  float mask = 1.f / (1.f + __expf(-(0.05f - stdv) * 10.f));
  if (lane == 0) mask_raw[row] = mask;
}

// ================= line filter apply (+optional tanh) =======================
__global__ __launch_bounds__(256) void k_lf_apply(
    const float* __restrict__ x, const float* __restrict__ mask_raw,
    float* __restrict__ out, int BC, int H, int W, float strength, int do_tanh)
{
  long idx = (long)blockIdx.x * 256 + threadIdx.x;
  long total = (long)BC * H * W;
  if (idx >= total) return;
  int wcol = (int)(idx % W);
  int h = (int)((idx / W) % H);
  int bc = (int)(idx / ((long)W * H));
  const float* px = x + (long)bc * H * W;
  const float* pm = mask_raw + (long)bc * H;
  float vs = 0.f, mb = 0.f;
#pragma unroll
  for (int d = -2; d <= 2; ++d) {
    int hh = h + d; hh = hh < 0 ? 0 : (hh >= H ? H - 1 : hh);
    vs += px[hh * W + wcol];
    mb += pm[hh];
  }
  vs *= 0.2f; mb *= 0.2f;
  float m = mb * strength;
  float o = x[idx] * (1.f - m) + vs * m;
  if (do_tanh) o = tanhf(o);
  out[idx] = o;
}

// ---------------- launch ----------------
static inline unsigned gdiv(long total) { return (unsigned)((total + 255) / 256); }

extern "C" void kernel_launch(void* const* d_in, const int* in_sizes, int n_in,
                              void* d_out, int out_size, void* d_ws, size_t ws_size,
                              hipStream_t stream)
{
  (void)in_sizes; (void)n_in; (void)out_size; (void)ws_size;
  const float* sketch   = (const float*)d_in[0];
  const float* depth    = (const float*)d_in[1];
  const float* style    = (const float*)d_in[2];
  const float* enc1_w   = (const float*)d_in[3];
  const float* enc1_b   = (const float*)d_in[4];
  const float* enc2_w   = (const float*)d_in[5];
  const float* enc2_b   = (const float*)d_in[6];
  const float* enc3_w   = (const float*)d_in[7];
  const float* enc3_b   = (const float*)d_in[8];
  const float* se1_w    = (const float*)d_in[9];
  const float* se1_b    = (const float*)d_in[10];
  const float* se2_w    = (const float*)d_in[11];
  const float* se2_b    = (const float*)d_in[12];
  const float* se3_w    = (const float*)d_in[13];
  const float* se3_b    = (const float*)d_in[14];
  const float* sp1_w    = (const float*)d_in[15];
  const float* sp1_b    = (const float*)d_in[16];
  const float* sp2_w    = (const float*)d_in[17];
  const float* sp2_b    = (const float*)d_in[18];
  const float* sm_w     = (const float*)d_in[19];
  const float* sm_b     = (const float*)d_in[20];
  const float* attn_q_w = (const float*)d_in[21];
  const float* attn_q_b = (const float*)d_in[22];
  const float* attn_k_w = (const float*)d_in[23];
  const float* attn_k_b = (const float*)d_in[24];
  const float* attn_v_w = (const float*)d_in[25];
  const float* attn_v_b = (const float*)d_in[26];
  const float* attn_g   = (const float*)d_in[27];
  const float* bn_w     = (const float*)d_in[28];
  const float* bn_b     = (const float*)d_in[29];
  const float* dec3_w   = (const float*)d_in[30];
  const float* dec3_b   = (const float*)d_in[31];
  const float* dec2_w   = (const float*)d_in[32];
  const float* dec2_b   = (const float*)d_in[33];
  const float* dec1_w   = (const float*)d_in[34];
  const float* dec1_b   = (const float*)d_in[35];
  float* out = (float*)d_out;

  float* ws    = (float*)d_ws;
  float* e1    = ws + OFF_E1;
  float* e2    = ws + OFF_E2;
  float* e3a   = ws + OFF_E3A;
  float* e3b   = ws + OFF_E3B;
  float* big16 = ws + OFF_BIG16;
  float* big8  = ws + OFF_BIG8;
  float* b4    = ws + OFF_B4;
  float* vbuf  = ws + OFF_V;
  float* qbuf  = ws + OFF_Q;
  float* kbuf  = ws + OFF_K;
  float* pool  = ws + OFF_POOL;
  float* sf1   = ws + OFF_SF1;
  float* sf2   = ws + OFF_SF2;
  float* rowst = ws + OFF_ROW;
  float* d2lf  = ws + OFF_D2LF;
  float* pre   = ws + OFF_PRE;

  const int B = 4;

  // ---- encoder ----
  k_c3<1,1,0, 2, 256,256,1, 2, 16,16, 1,0,0><<<dim3(256, B, 1), 256, 0, stream>>>(
      sketch, depth, enc1_w, enc1_b, nullptr, e1);
  k_c4<16,4,32,16, 256,256, 128,2><<<dim3(64, B, 2), 256, 0, stream>>>(e1, enc2_w, enc2_b, e2);
  k_c4<32,4,64,8, 128,128, 64,4><<<dim3(16, B, 8), 256, 0, stream>>>(e2, enc3_w, enc3_b, e3a);
  k_lf_rowstat<<<(B*64*64 + 3)/4, 256, 0, stream>>>(e3a, rowst, B*64*64, 64);
  k_lf_apply<<<gdiv((long)B*64*64*64), 256, 0, stream>>>(e3a, rowst, e3b, B*64, 64, 64, 0.8f, 0);

  // ---- style branch ----
  k_c3<3,0,0, 3, 256,256,1, 3, 16,16, 1,0,0><<<dim3(256, B, 1), 256, 0, stream>>>(
      style, nullptr, se1_w, se1_b, nullptr, big16);
  k_c4<16,4,32,16, 256,256, 128,2><<<dim3(64, B, 2), 256, 0, stream>>>(big16, se2_w, se2_b, big8);
  k_c4<32,4,64,8, 128,128, 64,4><<<dim3(16, B, 8), 256, 0, stream>>>(big8, se3_w, se3_b, b4);
  k_pool8<<<gdiv(B*64*64), 256, 0, stream>>>(b4, pool, B, 64, 64, 64);
  k_fc_relu<<<(B*64 + 3)/4, 256, 0, stream>>>(pool, sp1_w, sp1_b, sf1, B, 4096, 64);
  k_fc_relu<<<(B*64 + 3)/4, 256, 0, stream>>>(sf1, sp2_w, sp2_b, sf2, B, 64, 64);

  // ---- style merge (+mix fused, bcast channels via wsum) ----
  k_wsum<<<B, 256, 0, stream>>>(sm_w, sf2, pool);
  k_c3<64,0,0, 128, 64,64,4, 8, 64,8, 1,1,1><<<dim3(16, B, 8), 256, 0, stream>>>(
      e3b, nullptr, sm_w, sm_b, pool, e3a);

  // ---- self-attention on e3a -> e3b ----
  k_qkproj<<<64, 256, 0, stream>>>(e3a, attn_q_w, attn_q_b, attn_k_w, attn_k_b, qbuf, kbuf, 4096);
  k_vprojT<<<64, 256, 0, stream>>>(e3a, attn_v_w, attn_v_b, vbuf, 4096);
  k_fattn<<<dim3(256, B), 256, 0, stream>>>(qbuf, kbuf, vbuf, e3a, attn_g, e3b, 4096);

  // ---- bottleneck + decoder ----
  k_c3<64,0,0, 64, 64,64,4, 8, 64,8, 1,0,0><<<dim3(16, B, 8), 256, 0, stream>>>(
      e3b, nullptr, bn_w, bn_b, nullptr, b4);
  k_ct<64,64,32,4, 64,64, 4,8><<<dim3(16, B, 8), 256, 0, stream>>>(b4, e3b, dec3_w, dec3_b, big8);
  k_ct<32,32,16,8, 128,128, 2,8><<<dim3(64, B, 2), 256, 0, stream>>>(big8, e2, dec2_w, dec2_b, big16);
  k_lf_rowstat<<<(B*16*256 + 3)/4, 256, 0, stream>>>(big16, rowst, B*16*256, 256);
  k_lf_apply<<<gdiv((long)B*16*256*256), 256, 0, stream>>>(big16, rowst, d2lf, B*16, 256, 256, 0.8f, 0);
  k_c3<16,16,0, 32, 256,256,1, 8, 3,3, 0,0,0><<<dim3(256, B, 1), 256, 0, stream>>>(
      d2lf, e1, dec1_w, dec1_b, nullptr, pre);
  k_lf_rowstat<<<(B*3*256 + 3)/4, 256, 0, stream>>>(pre, rowst, B*3*256, 256);
  k_lf_apply<<<gdiv((long)B*3*256*256), 256, 0, stream>>>(pre, rowst, out, B*3, 256, 256, 0.9f, 1);
}

// Round 5
// 1356.809 us; speedup vs baseline: 2.9474x; 1.0347x over previous
//
#include <hip/hip_runtime.h>
#include <cstdint>
#include <cstddef>

// ---------------- workspace layout (floats) ----------------
static const size_t OFF_E1    = 0;         // [4,16,256,256]
static const size_t OFF_E2    = 4194304;   // [4,32,128,128]
static const size_t OFF_E3A   = 6291456;   // [4,64,64,64]
static const size_t OFF_E3B   = 7340032;   // [4,64,64,64]
static const size_t OFF_BIG16 = 8388608;   // s1 then d2raw
static const size_t OFF_BIG8  = 12582912;  // s2 then d3
static const size_t OFF_B4    = 14680064;  // s3 then bn-out
static const size_t OFF_V     = 15728640;  // vT [4,4096,64]
static const size_t OFF_Q     = 16777216;  // qT [4,4096,8]
static const size_t OFF_K     = 16908288;  // kC [4,8,4096]
static const size_t OFF_POOL  = 17039360;  // pool then wsum[4][64][9]
static const size_t OFF_SF1   = 17055744;
static const size_t OFF_SF2   = 17056000;
static const size_t OFF_ROW   = 17056256;
static const size_t OFF_D2LF  = 17072640;  // [4,16,256,256]
static const size_t OFF_PRE   = 21266944;  // [4,3,256,256]

// ============== conv3x3 s1 p1, LDS-staged, multi-co per thread ==============
template<int C1, int C2, int BCAST2, int CIN_W, int W, int H, int ROWS,
         int CI_CH, int COUT, int CO_T, int RELU, int MIX, int WSUM>
__global__ __launch_bounds__(256) void k_c3(
    const float* __restrict__ in1, const float* __restrict__ in2,
    const float* __restrict__ w, const float* __restrict__ bias,
    const float* __restrict__ wsum, float* __restrict__ out)
{
  constexpr int CIN = C1 + C2;
  constexpr int PW = W + 4;
  constexpr int LR = ROWS + 2;
  __shared__ float lds[CI_CH * LR * PW];

  int tid = threadIdx.x;
  int tx = tid % W, ty = tid / W;
  int b = blockIdx.y;
  int co0 = blockIdx.z * CO_T;
  int oh0 = blockIdx.x * ROWS;
  int oh = oh0 + ty;

  float acc[CO_T];
#pragma unroll
  for (int i = 0; i < CO_T; ++i) acc[i] = bias[co0 + i];

  if (WSUM) {
    bool rv0 = oh - 1 >= 0, rv2 = oh + 1 < H;
    bool cv0 = tx - 1 >= 0, cv2 = tx + 1 < W;
    bool rv[3] = {rv0, true, rv2};
    bool cv[3] = {cv0, true, cv2};
    const float* wsp = wsum + ((long)b * COUT + co0) * 9;
#pragma unroll
    for (int co = 0; co < CO_T; ++co)
#pragma unroll
      for (int ky = 0; ky < 3; ++ky)
#pragma unroll
        for (int kx = 0; kx < 3; ++kx)
          acc[co] += (rv[ky] && cv[kx]) ? wsp[co * 9 + ky * 3 + kx] : 0.f;
  }

  for (int c0 = 0; c0 < CIN; c0 += CI_CH) {
    constexpr int TOTAL = CI_CH * LR * PW;
    for (int i = tid; i < TOTAL; i += 256) {
      int ci_l = i / (LR * PW);
      int rem = i % (LR * PW);
      int r = rem / PW, c = rem % PW;
      int ih = oh0 - 1 + r, iw = c - 1;
      int ci = c0 + ci_l;
      float v = 0.f;
      if ((unsigned)ih < (unsigned)H && (unsigned)iw < (unsigned)W) {
        if (ci < C1) v = in1[((long)(b * C1 + ci) * H + ih) * W + iw];
        else if (BCAST2) v = in2[b * C2 + ci - C1];
        else v = in2[((long)(b * C2 + ci - C1) * H + ih) * W + iw];
      }
      lds[i] = v;
    }
    __syncthreads();
#pragma unroll
    for (int ci_l = 0; ci_l < CI_CH; ++ci_l) {
      int ci = c0 + ci_l;
      float x[3][3];
#pragma unroll
      for (int ky = 0; ky < 3; ++ky)
#pragma unroll
        for (int kx = 0; kx < 3; ++kx)
          x[ky][kx] = lds[ci_l * (LR * PW) + (ty + ky) * PW + tx + kx];
      const float* wb = w + (long)ci * 9;
#pragma unroll
      for (int co = 0; co < CO_T; ++co) {
        const float* wp = wb + (long)(co0 + co) * CIN_W * 9;
#pragma unroll
        for (int ky = 0; ky < 3; ++ky)
#pragma unroll
          for (int kx = 0; kx < 3; ++kx)
            acc[co] += wp[ky * 3 + kx] * x[ky][kx];
      }
    }
    __syncthreads();
  }

#pragma unroll
  for (int co = 0; co < CO_T; ++co) {
    float a = acc[co];
    if (RELU) a = fmaxf(a, 0.f);
    if (MIX) {
      float m = in1[((long)(b * C1 + co0 + co) * H + oh) * W + tx];
      a = 0.99f * m + 0.01f * a;
    }
    out[((long)(b * COUT + co0 + co) * H + oh) * W + tx] = a;
  }
}

// ============== conv4x4 s2 p1 + relu, LDS-staged =============================
template<int CIN, int CI_CH, int COUT, int CO_T, int WIN, int HIN, int TW, int TH>
__global__ __launch_bounds__(256) void k_c4(
    const float* __restrict__ in, const float* __restrict__ w,
    const float* __restrict__ bias, float* __restrict__ out)
{
  constexpr int Wo = WIN / 2, Ho = HIN / 2;
  constexpr int PW = 2 * TW + 4;
  constexpr int LR = 2 * TH + 2;
  __shared__ float lds[CI_CH * LR * PW];

  int tid = threadIdx.x;
  int tx = tid % TW, ty = tid / TW;
  int b = blockIdx.y;
  int co0 = blockIdx.z * CO_T;
  int oh0 = blockIdx.x * TH;
  int oh = oh0 + ty;
  int R0 = 2 * oh0 - 1;

  float acc[CO_T];
#pragma unroll
  for (int i = 0; i < CO_T; ++i) acc[i] = bias[co0 + i];

  for (int c0 = 0; c0 < CIN; c0 += CI_CH) {
    constexpr int TOTAL = CI_CH * LR * PW;
    for (int i = tid; i < TOTAL; i += 256) {
      int ci_l = i / (LR * PW);
      int rem = i % (LR * PW);
      int r = rem / PW, c = rem % PW;
      int ih = R0 + r, iw = c - 1;
      float v = 0.f;
      if ((unsigned)ih < (unsigned)HIN && (unsigned)iw < (unsigned)WIN)
        v = in[((long)(b * CIN + c0 + ci_l) * HIN + ih) * WIN + iw];
      lds[i] = v;
    }
    __syncthreads();
#pragma unroll
    for (int ci_l = 0; ci_l < CI_CH; ++ci_l) {
      int ci = c0 + ci_l;
      float x[4][4];
#pragma unroll
      for (int ky = 0; ky < 4; ++ky)
#pragma unroll
        for (int kx = 0; kx < 4; ++kx)
          x[ky][kx] = lds[ci_l * (LR * PW) + (2 * ty + ky) * PW + 2 * tx + kx];
      const float* wb = w + (long)ci * 16;
#pragma unroll
      for (int co = 0; co < CO_T; ++co) {
        const float* wp = wb + (long)(co0 + co) * CIN * 16;
#pragma unroll
        for (int ky = 0; ky < 4; ++ky)
#pragma unroll
          for (int kx = 0; kx < 4; ++kx)
            acc[co] += wp[ky * 4 + kx] * x[ky][kx];
      }
    }
    __syncthreads();
  }

#pragma unroll
  for (int co = 0; co < CO_T; ++co)
    out[((long)(b * COUT + co0 + co) * Ho + oh) * Wo + tx] = fmaxf(acc[co], 0.f);
}

// ============== convT 4x4 s2 p1 + relu, LDS-staged, 2x2 outputs/thread ======
template<int C1, int C2, int COUT, int CO_T, int WIN, int HIN, int TPR, int CI_CH>
__global__ __launch_bounds__(256) void k_ct(
    const float* __restrict__ in1, const float* __restrict__ in2,
    const float* __restrict__ w, const float* __restrict__ bias,
    float* __restrict__ out)
{
  constexpr int CIN = C1 + C2;
  constexpr int Wo = 2 * WIN, Ho = 2 * HIN;
  constexpr int PW = WIN + 4;
  constexpr int LR = TPR + 2;
  __shared__ float lds[CI_CH * LR * PW];

  int tid = threadIdx.x;
  int s = tid % WIN, dt = tid / WIN;
  int b = blockIdx.y;
  int co0 = blockIdx.z * CO_T;
  int t0 = blockIdx.x * TPR;
  int t = t0 + dt;

  float aee[CO_T], aeo[CO_T], aoe[CO_T], aoo[CO_T];
#pragma unroll
  for (int i = 0; i < CO_T; ++i) {
    float bb = bias[co0 + i];
    aee[i] = bb; aeo[i] = bb; aoe[i] = bb; aoo[i] = bb;
  }

  for (int c0 = 0; c0 < CIN; c0 += CI_CH) {
    constexpr int TOTAL = CI_CH * LR * PW;
    for (int i = tid; i < TOTAL; i += 256) {
      int ci_l = i / (LR * PW);
      int rem = i % (LR * PW);
      int r = rem / PW, c = rem % PW;
      int ih = t0 - 1 + r, iw = c - 1;
      int ci = c0 + ci_l;
      float v = 0.f;
      if ((unsigned)ih < (unsigned)HIN && (unsigned)iw < (unsigned)WIN) {
        if (ci < C1) v = in1[((long)(b * C1 + ci) * HIN + ih) * WIN + iw];
        else v = in2[((long)(b * C2 + ci - C1) * HIN + ih) * WIN + iw];
      }
      lds[i] = v;
    }
    __syncthreads();
#pragma unroll
    for (int ci_l = 0; ci_l < CI_CH; ++ci_l) {
      int ci = c0 + ci_l;
      float x[3][3];
#pragma unroll
      for (int r = 0; r < 3; ++r)
#pragma unroll
        for (int c = 0; c < 3; ++c)
          x[r][c] = lds[ci_l * (LR * PW) + (dt + r) * PW + s + c];
      const float* wb = w + (long)ci * COUT * 16;
#pragma unroll
      for (int co = 0; co < CO_T; ++co) {
        const float* wp = wb + (long)(co0 + co) * 16;
        float w00 = wp[0],  w01 = wp[1],  w02 = wp[2],  w03 = wp[3];
        float w10 = wp[4],  w11 = wp[5],  w12 = wp[6],  w13 = wp[7];
        float w20 = wp[8],  w21 = wp[9],  w22 = wp[10], w23 = wp[11];
        float w30 = wp[12], w31 = wp[13], w32 = wp[14], w33 = wp[15];
        aee[co] += w11 * x[1][1] + w13 * x[1][0] + w31 * x[0][1] + w33 * x[0][0];
        aeo[co] += w10 * x[1][2] + w12 * x[1][1] + w30 * x[0][2] + w32 * x[0][1];
        aoe[co] += w01 * x[2][1] + w03 * x[2][0] + w21 * x[1][1] + w23 * x[1][0];
        aoo[co] += w00 * x[2][2] + w02 * x[2][1] + w20 * x[1][2] + w22 * x[1][1];
      }
    }
    __syncthreads();
  }

#pragma unroll
  for (int co = 0; co < CO_T; ++co) {
    long base = ((long)(b * COUT + co0 + co) * Ho + 2 * t) * Wo + 2 * s;
    float2 r0; r0.x = fmaxf(aee[co], 0.f); r0.y = fmaxf(aeo[co], 0.f);
    float2 r1; r1.x = fmaxf(aoe[co], 0.f); r1.y = fmaxf(aoo[co], 0.f);
    *(float2*)(out + base) = r0;
    *(float2*)(out + base + Wo) = r1;
  }
}

// ============== wsum precompute for style-merge broadcast channels ==========
__global__ __launch_bounds__(256) void k_wsum(
    const float* __restrict__ w, const float* __restrict__ sf,
    float* __restrict__ wsum)
{
  int b = blockIdx.x;
  for (int i = threadIdx.x; i < 576; i += 256) {
    int co = i / 9, t = i % 9;
    float s = 0.f;
    for (int ci = 0; ci < 64; ++ci)
      s += w[((long)co * 128 + 64 + ci) * 9 + t] * sf[b * 64 + ci];
    wsum[((long)b * 64 + co) * 9 + t] = s;
  }
}

// ============== q/k projection -> qT [B][N][8], kC [B][8][N] ================
__global__ __launch_bounds__(256) void k_qkproj(
    const float* __restrict__ x, const float* __restrict__ wq,
    const float* __restrict__ bq, const float* __restrict__ wk,
    const float* __restrict__ bk, float* __restrict__ qT,
    float* __restrict__ kC, int N)
{
  int idx = blockIdx.x * 256 + threadIdx.x;
  int n = idx % N, b = idx / N;
  float qa[8], ka[8];
#pragma unroll
  for (int c = 0; c < 8; ++c) { qa[c] = bq[c]; ka[c] = bk[c]; }
  const float* src = x + (long)b * 64 * N + n;
  for (int ci = 0; ci < 64; ++ci) {
    float xv = src[(long)ci * N];
#pragma unroll
    for (int c = 0; c < 8; ++c) {
      qa[c] += wq[c * 64 + ci] * xv;
      ka[c] += wk[c * 64 + ci] * xv;
    }
  }
  float* qo = qT + ((long)b * N + n) * 8;
#pragma unroll
  for (int c = 0; c < 8; ++c) qo[c] = qa[c];
#pragma unroll
  for (int c = 0; c < 8; ++c) kC[((long)b * 8 + c) * N + n] = ka[c];
}

// ============== V projection -> vT [B][N][64], c-quarter split ==============
__global__ __launch_bounds__(256) void k_vprojT(
    const float* __restrict__ x, const float* __restrict__ w,
    const float* __restrict__ bias, float* __restrict__ vT, int N)
{
  int idx = blockIdx.x * 256 + threadIdx.x;
  int cq = blockIdx.y * 16;
  int n = idx % N, b = idx / N;
  float va[16];
#pragma unroll
  for (int c = 0; c < 16; ++c) va[c] = bias[cq + c];
  const float* src = x + (long)b * 64 * N + n;
  for (int ci = 0; ci < 64; ++ci) {
    float xv = src[(long)ci * N];
#pragma unroll
    for (int c = 0; c < 16; ++c) va[c] += w[(cq + c) * 64 + ci] * xv;
  }
  float* vo = vT + ((long)b * N + n) * 64 + cq;
#pragma unroll
  for (int c = 0; c < 16; c += 4) {
    float4 o; o.x = va[c]; o.y = va[c+1]; o.z = va[c+2]; o.w = va[c+3];
    *(float4*)(vo + c) = o;
  }
}

// ============== flash attention v2: TQ=64, 4q x 4c register tile ============
// 256 threads: qg = tid>>4 (4 q-rows each), xg = tid&15 (m-group in QK, c-group in PV)
// no-max softmax: softmax(e) = exp(e)/sum(exp(e)) exactly (range is small, fp32-safe)
__global__ __launch_bounds__(256) void k_fattn(
    const float* __restrict__ qT, const float* __restrict__ kC,
    const float* __restrict__ vT, const float* __restrict__ xb,
    const float* __restrict__ gamma_p, float* __restrict__ outb, int N)
{
  __shared__ float k_s[8][68];
  __shared__ float v_s[64 * 64];   // [m][c]
  __shared__ float p_s[64][68];    // [m][q]; reused as o_s[64][68] = [c][q]

  int tid = threadIdx.x;
  int b = blockIdx.x >> 6;
  int n0 = (blockIdx.x & 63) * 64;
  int qg = tid >> 4;
  int xg = tid & 15;

  // q regs: 4 rows x 8 channels
  float qv[4][8];
#pragma unroll
  for (int i = 0; i < 4; ++i) {
    const float4* qp = (const float4*)(qT + ((long)b * N + n0 + qg * 4 + i) * 8);
    float4 a = qp[0], c = qp[1];
    qv[i][0]=a.x; qv[i][1]=a.y; qv[i][2]=a.z; qv[i][3]=a.w;
    qv[i][4]=c.x; qv[i][5]=c.y; qv[i][6]=c.z; qv[i][7]=c.w;
  }

  float o[4][4];
#pragma unroll
  for (int i = 0; i < 4; ++i)
#pragma unroll
    for (int j = 0; j < 4; ++j) o[i][j] = 0.f;
  float l[4] = {0.f, 0.f, 0.f, 0.f};

  const float* kbase = kC + (long)b * 8 * N;
  const float* vbase = vT + (long)b * N * 64;

  for (int t = 0; t < 64; ++t) {
    int m0 = t * 64;
    // issue V loads to regs (latency hidden under QK)
    float4 vr0, vr1, vr2, vr3;
    {
      const float4* vp = (const float4*)(vbase + (long)m0 * 64) + tid;
      vr0 = vp[0]; vr1 = vp[256]; vr2 = vp[512]; vr3 = vp[768];
    }
    // stage K tile [8][64]: thread -> (kk = tid>>5, seg = tid&31) float2
    {
      int kk = tid >> 5, seg = tid & 31;
      float2 kv2 = *(const float2*)(kbase + (long)kk * N + m0 + seg * 2);
      *(float2*)&k_s[kk][seg * 2] = kv2;
    }
    __syncthreads();   // (A) k_s ready; prev PV done (v_s/p_s safe to overwrite)

    // QK^T: s[4q][4m] for m = xg*4..+3
    float s0[4], s1[4], s2[4], s3[4];
#pragma unroll
    for (int i = 0; i < 4; ++i) { s0[i]=0.f; s1[i]=0.f; s2[i]=0.f; s3[i]=0.f; }
#pragma unroll
    for (int kk = 0; kk < 8; ++kk) {
      float4 kx = *(const float4*)&k_s[kk][xg * 4];
#pragma unroll
      for (int i = 0; i < 4; ++i) {
        float q = qv[i][kk];
        s0[i] += q * kx.x; s1[i] += q * kx.y; s2[i] += q * kx.z; s3[i] += q * kx.w;
      }
    }
    // exp + partial row sums (no max subtraction), write P transposed [m][q]
    float p0[4], p1[4], p2[4], p3[4];
#pragma unroll
    for (int i = 0; i < 4; ++i) {
      p0[i] = __expf(s0[i]); p1[i] = __expf(s1[i]);
      p2[i] = __expf(s2[i]); p3[i] = __expf(s3[i]);
      l[i] += p0[i] + p1[i] + p2[i] + p3[i];
    }
    {
      float4 w0; w0.x=p0[0]; w0.y=p0[1]; w0.z=p0[2]; w0.w=p0[3];
      float4 w1; w1.x=p1[0]; w1.y=p1[1]; w1.z=p1[2]; w1.w=p1[3];
      float4 w2; w2.x=p2[0]; w2.y=p2[1]; w2.z=p2[2]; w2.w=p2[3];
      float4 w3; w3.x=p3[0]; w3.y=p3[1]; w3.z=p3[2]; w3.w=p3[3];
      *(float4*)&p_s[xg * 4 + 0][qg * 4] = w0;
      *(float4*)&p_s[xg * 4 + 1][qg * 4] = w1;
      *(float4*)&p_s[xg * 4 + 2][qg * 4] = w2;
      *(float4*)&p_s[xg * 4 + 3][qg * 4] = w3;
    }
    // commit V regs to LDS
    {
      float* vd = v_s + tid * 4;
      *(float4*)(vd +    0) = vr0;
      *(float4*)(vd + 1024) = vr1;
      *(float4*)(vd + 2048) = vr2;
      *(float4*)(vd + 3072) = vr3;
    }
    __syncthreads();   // (B) p_s + v_s ready

    // PV: o[4q][4c] for c = xg*4..+3
#pragma unroll 2
    for (int mm = 0; mm < 16; ++mm) {
#pragma unroll
      for (int j = 0; j < 4; ++j) {
        int m = mm * 4 + j;
        float4 pj = *(const float4*)&p_s[m][qg * 4];
        float4 vj = *(const float4*)&v_s[m * 64 + xg * 4];
        o[0][0] += pj.x * vj.x; o[0][1] += pj.x * vj.y; o[0][2] += pj.x * vj.z; o[0][3] += pj.x * vj.w;
        o[1][0] += pj.y * vj.x; o[1][1] += pj.y * vj.y; o[1][2] += pj.y * vj.z; o[1][3] += pj.y * vj.w;
        o[2][0] += pj.z * vj.x; o[2][1] += pj.z * vj.y; o[2][2] += pj.z * vj.z; o[2][3] += pj.z * vj.w;
        o[3][0] += pj.w * vj.x; o[3][1] += pj.w * vj.y; o[3][2] += pj.w * vj.z; o[3][3] += pj.w * vj.w;
      }
    }
    __syncthreads();   // protect p_s/v_s until PV of all waves done
  }

  // final row sums: reduce l over the 16 m-group lanes (same qg)
#pragma unroll
  for (int i = 0; i < 4; ++i) {
#pragma unroll
    for (int d = 1; d < 16; d <<= 1) l[i] += __shfl_xor(l[i], d);
  }
  float g = gamma_p[0];
  float inv[4];
#pragma unroll
  for (int i = 0; i < 4; ++i) inv[i] = g / l[i];

  // write o (scaled) transposed into o_s[c][q] (reuse p_s)
#pragma unroll
  for (int j = 0; j < 4; ++j) {
    float4 w4;
    w4.x = o[0][j] * inv[0]; w4.y = o[1][j] * inv[1];
    w4.z = o[2][j] * inv[2]; w4.w = o[3][j] * inv[3];
    *(float4*)&p_s[xg * 4 + j][qg * 4] = w4;
  }
  __syncthreads();
  // epilogue: out[b][c][n0+q] = o_s[c][q] + x
  for (int idx = tid; idx < 4096; idx += 256) {
    int c = idx >> 6, q = idx & 63;
    long off = ((long)b * 64 + c) * N + n0 + q;
    outb[off] = p_s[c][q] + xb[off];
  }
}

// ================= adaptive avg pool to 8x8 ================================
__global__ __launch_bounds__(256) void k_pool8(
    const float* __restrict__ in, float* __restrict__ out, int B, int C, int H, int W)
{
  int idx = blockIdx.x * 256 + threadIdx.x;
  int total = B * C * 64;
  if (idx >= total) return;
  int ow = idx & 7, oh = (idx >> 3) & 7;
  int c = (idx >> 6) % C, b = idx / (64 * C);
  int bh = H / 8, bw = W / 8;
  const float* src = in + ((long)(b * C + c)) * H * W;
  float s = 0.f;
  for (int y = 0; y < bh; ++y)
    for (int x = 0; x < bw; ++x)
      s += src[(oh * bh + y) * W + ow * bw + x];
  out[idx] = s / (float)(bh * bw);
}

// ================= fc + relu (wave per output) ==============================
__global__ __launch_bounds__(256) void k_fc_relu(
    const float* __restrict__ in, const float* __restrict__ w,
    const float* __restrict__ bias, float* __restrict__ out, int B, int K, int O)
{
  int gi = blockIdx.x * 4 + (threadIdx.x >> 6);
  int lane = threadIdx.x & 63;
  if (gi >= B * O) return;
  int b = gi / O, o = gi % O;
  const float* x = in + (long)b * K;
  const float* wp = w + (long)o * K;
  float s = 0.f;
  for (int i = lane; i < K; i += 64) s += x[i] * wp[i];
#pragma unroll
  for (int d = 1; d < 64; d <<= 1) s += __shfl_xor(s, d);
  if (lane == 0) out[gi] = fmaxf(s + bias[o], 0.f);
}

// ================= line filter: per-row std -> sigmoid mask =================
__global__ __launch_bounds__(256) void k_lf_rowstat(
    const float* __restrict__ x, float* __restrict__ mask_raw, int rows, int W)
{
  int row = blockIdx.x * 4 + (threadIdx.x >> 6);
  int lane = threadIdx.x & 63;
  if (row >= rows) return;
  const float* p = x + (long)row * W;
  float s = 0.f;
  for (int i = lane; i < W; i += 64) s += p[i];
#pragma unroll
  for (int d = 1; d < 64; d <<= 1) s += __shfl_xor(s, d);
  float mean = s / (float)W;
  float v = 0.f;
  for (int i = lane; i < W; i += 64) { float t = p[i] - mean; v += t * t; }
#pragma unroll
  for (int d = 1; d < 64; d <<= 1) v += __shfl_xor(v, d);
  float stdv = sqrtf(v / (float)(W - 1));
  float mask = 1.f / (1.f + __expf(-(0.05f - stdv) * 10.f));
  if (lane == 0) mask_raw[row] = mask;
}

// ================= line filter apply (+optional tanh) =======================
__global__ __launch_bounds__(256) void k_lf_apply(
    const float* __restrict__ x, const float* __restrict__ mask_raw,
    float* __restrict__ out, int BC, int H, int W, float strength, int do_tanh)
{
  long idx = (long)blockIdx.x * 256 + threadIdx.x;
  long total = (long)BC * H * W;
  if (idx >= total) return;
  int wcol = (int)(idx % W);
  int h = (int)((idx / W) % H);
  int bc = (int)(idx / ((long)W * H));
  const float* px = x + (long)bc * H * W;
  const float* pm = mask_raw + (long)bc * H;
  float vs = 0.f, mb = 0.f;
#pragma unroll
  for (int d = -2; d <= 2; ++d) {
    int hh = h + d; hh = hh < 0 ? 0 : (hh >= H ? H - 1 : hh);
    vs += px[hh * W + wcol];
    mb += pm[hh];
  }
  vs *= 0.2f; mb *= 0.2f;
  float m = mb * strength;
  float o = x[idx] * (1.f - m) + vs * m;
  if (do_tanh) o = tanhf(o);
  out[idx] = o;
}

// ---------------- launch ----------------
static inline unsigned gdiv(long total) { return (unsigned)((total + 255) / 256); }

extern "C" void kernel_launch(void* const* d_in, const int* in_sizes, int n_in,
                              void* d_out, int out_size, void* d_ws, size_t ws_size,
                              hipStream_t stream)
{
  (void)in_sizes; (void)n_in; (void)out_size; (void)ws_size;
  const float* sketch   = (const float*)d_in[0];
  const float* depth    = (const float*)d_in[1];
  const float* style    = (const float*)d_in[2];
  const float* enc1_w   = (const float*)d_in[3];
  const float* enc1_b   = (const float*)d_in[4];
  const float* enc2_w   = (const float*)d_in[5];
  const float* enc2_b   = (const float*)d_in[6];
  const float* enc3_w   = (const float*)d_in[7];
  const float* enc3_b   = (const float*)d_in[8];
  const float* se1_w    = (const float*)d_in[9];
  const float* se1_b    = (const float*)d_in[10];
  const float* se2_w    = (const float*)d_in[11];
  const float* se2_b    = (const float*)d_in[12];
  const float* se3_w    = (const float*)d_in[13];
  const float* se3_b    = (const float*)d_in[14];
  const float* sp1_w    = (const float*)d_in[15];
  const float* sp1_b    = (const float*)d_in[16];
  const float* sp2_w    = (const float*)d_in[17];
  const float* sp2_b    = (const float*)d_in[18];
  const float* sm_w     = (const float*)d_in[19];
  const float* sm_b     = (const float*)d_in[20];
  const float* attn_q_w = (const float*)d_in[21];
  const float* attn_q_b = (const float*)d_in[22];
  const float* attn_k_w = (const float*)d_in[23];
  const float* attn_k_b = (const float*)d_in[24];
  const float* attn_v_w = (const float*)d_in[25];
  const float* attn_v_b = (const float*)d_in[26];
  const float* attn_g   = (const float*)d_in[27];
  const float* bn_w     = (const float*)d_in[28];
  const float* bn_b     = (const float*)d_in[29];
  const float* dec3_w   = (const float*)d_in[30];
  const float* dec3_b   = (const float*)d_in[31];
  const float* dec2_w   = (const float*)d_in[32];
  const float* dec2_b   = (const float*)d_in[33];
  const float* dec1_w   = (const float*)d_in[34];
  const float* dec1_b   = (const float*)d_in[35];
  float* out = (float*)d_out;

  float* ws    = (float*)d_ws;
  float* e1    = ws + OFF_E1;
  float* e2    = ws + OFF_E2;
  float* e3a   = ws + OFF_E3A;
  float* e3b   = ws + OFF_E3B;
  float* big16 = ws + OFF_BIG16;
  float* big8  = ws + OFF_BIG8;
  float* b4    = ws + OFF_B4;
  float* vbuf  = ws + OFF_V;
  float* qbuf  = ws + OFF_Q;
  float* kbuf  = ws + OFF_K;
  float* pool  = ws + OFF_POOL;
  float* sf1   = ws + OFF_SF1;
  float* sf2   = ws + OFF_SF2;
  float* rowst = ws + OFF_ROW;
  float* d2lf  = ws + OFF_D2LF;
  float* pre   = ws + OFF_PRE;

  const int B = 4;

  // ---- encoder ----
  k_c3<1,1,0, 2, 256,256,1, 2, 16,16, 1,0,0><<<dim3(256, B, 1), 256, 0, stream>>>(
      sketch, depth, enc1_w, enc1_b, nullptr, e1);
  k_c4<16,4,32,16, 256,256, 128,2><<<dim3(64, B, 2), 256, 0, stream>>>(e1, enc2_w, enc2_b, e2);
  k_c4<32,4,64,8, 128,128, 64,4><<<dim3(16, B, 8), 256, 0, stream>>>(e2, enc3_w, enc3_b, e3a);
  k_lf_rowstat<<<(B*64*64 + 3)/4, 256, 0, stream>>>(e3a, rowst, B*64*64, 64);
  k_lf_apply<<<gdiv((long)B*64*64*64), 256, 0, stream>>>(e3a, rowst, e3b, B*64, 64, 64, 0.8f, 0);

  // ---- style branch ----
  k_c3<3,0,0, 3, 256,256,1, 3, 16,16, 1,0,0><<<dim3(256, B, 1), 256, 0, stream>>>(
      style, nullptr, se1_w, se1_b, nullptr, big16);
  k_c4<16,4,32,16, 256,256, 128,2><<<dim3(64, B, 2), 256, 0, stream>>>(big16, se2_w, se2_b, big8);
  k_c4<32,4,64,8, 128,128, 64,4><<<dim3(16, B, 8), 256, 0, stream>>>(big8, se3_w, se3_b, b4);
  k_pool8<<<gdiv(B*64*64), 256, 0, stream>>>(b4, pool, B, 64, 64, 64);
  k_fc_relu<<<(B*64 + 3)/4, 256, 0, stream>>>(pool, sp1_w, sp1_b, sf1, B, 4096, 64);
  k_fc_relu<<<(B*64 + 3)/4, 256, 0, stream>>>(sf1, sp2_w, sp2_b, sf2, B, 64, 64);

  // ---- style merge (+mix fused, bcast channels via wsum) ----
  k_wsum<<<B, 256, 0, stream>>>(sm_w, sf2, pool);
  k_c3<64,0,0, 128, 64,64,4, 8, 64,8, 1,1,1><<<dim3(16, B, 8), 256, 0, stream>>>(
      e3b, nullptr, sm_w, sm_b, pool, e3a);

  // ---- self-attention on e3a -> e3b ----
  k_qkproj<<<64, 256, 0, stream>>>(e3a, attn_q_w, attn_q_b, attn_k_w, attn_k_b, qbuf, kbuf, 4096);
  k_vprojT<<<dim3(64, 4), 256, 0, stream>>>(e3a, attn_v_w, attn_v_b, vbuf, 4096);
  k_fattn<<<B * 64, 256, 0, stream>>>(qbuf, kbuf, vbuf, e3a, attn_g, e3b, 4096);

  // ---- bottleneck + decoder ----
  k_c3<64,0,0, 64, 64,64,4, 8, 64,8, 1,0,0><<<dim3(16, B, 8), 256, 0, stream>>>(
      e3b, nullptr, bn_w, bn_b, nullptr, b4);
  k_ct<64,64,32,4, 64,64, 4,8><<<dim3(16, B, 8), 256, 0, stream>>>(b4, e3b, dec3_w, dec3_b, big8);
  k_ct<32,32,16,8, 128,128, 2,8><<<dim3(64, B, 2), 256, 0, stream>>>(big8, e2, dec2_w, dec2_b, big16);
  k_lf_rowstat<<<(B*16*256 + 3)/4, 256, 0, stream>>>(big16, rowst, B*16*256, 256);
  k_lf_apply<<<gdiv((long)B*16*256*256), 256, 0, stream>>>(big16, rowst, d2lf, B*16, 256, 256, 0.8f, 0);
  k_c3<16,16,0, 32, 256,256,1, 8, 3,3, 0,0,0><<<dim3(256, B, 1), 256, 0, stream>>>(
      d2lf, e1, dec1_w, dec1_b, nullptr, pre);
  k_lf_rowstat<<<(B*3*256 + 3)/4, 256, 0, stream>>>(pre, rowst, B*3*256, 256);
  k_lf_apply<<<gdiv((long)B*3*256*256), 256, 0, stream>>>(pre, rowst, out, B*3, 256, 256, 0.9f, 1);
}

// Round 6
// 929.883 us; speedup vs baseline: 4.3007x; 1.4591x over previous
//
#include <hip/hip_runtime.h>
#include <cstdint>
#include <cstddef>

// ---------------- workspace layout (floats) ----------------
static const size_t OFF_E1    = 0;         // [4,16,256,256]
static const size_t OFF_E2    = 4194304;   // [4,32,128,128]
static const size_t OFF_E3A   = 6291456;   // [4,64,64,64]
static const size_t OFF_E3B   = 7340032;   // [4,64,64,64]
static const size_t OFF_BIG16 = 8388608;   // s1 then d2raw
static const size_t OFF_BIG8  = 12582912;  // s2 then d3
static const size_t OFF_B4    = 14680064;  // s3 then bn-out
static const size_t OFF_V     = 15728640;  // vT [4,4096,64]
static const size_t OFF_Q     = 16777216;  // qT [4,4096,8]
static const size_t OFF_K     = 16908288;  // kC [4,8,4096]
static const size_t OFF_POOL  = 17039360;  // pool then wsum[4][64][9]
static const size_t OFF_SF1   = 17055744;
static const size_t OFF_SF2   = 17056000;
static const size_t OFF_ROW   = 17056256;
static const size_t OFF_D2LF  = 17072640;  // [4,16,256,256]
static const size_t OFF_PRE   = 21266944;  // [4,3,256,256]

// ============== conv3x3 s1 p1, LDS-staged, multi-co per thread ==============
template<int C1, int C2, int BCAST2, int CIN_W, int W, int H, int ROWS,
         int CI_CH, int COUT, int CO_T, int RELU, int MIX, int WSUM>
__global__ __launch_bounds__(256) void k_c3(
    const float* __restrict__ in1, const float* __restrict__ in2,
    const float* __restrict__ w, const float* __restrict__ bias,
    const float* __restrict__ wsum, float* __restrict__ out)
{
  constexpr int CIN = C1 + C2;
  constexpr int PW = W + 4;
  constexpr int LR = ROWS + 2;
  __shared__ float lds[CI_CH * LR * PW];

  int tid = threadIdx.x;
  int tx = tid % W, ty = tid / W;
  int b = blockIdx.y;
  int co0 = blockIdx.z * CO_T;
  int oh0 = blockIdx.x * ROWS;
  int oh = oh0 + ty;

  float acc[CO_T];
#pragma unroll
  for (int i = 0; i < CO_T; ++i) acc[i] = bias[co0 + i];

  if (WSUM) {
    bool rv0 = oh - 1 >= 0, rv2 = oh + 1 < H;
    bool cv0 = tx - 1 >= 0, cv2 = tx + 1 < W;
    bool rv[3] = {rv0, true, rv2};
    bool cv[3] = {cv0, true, cv2};
    const float* wsp = wsum + ((long)b * COUT + co0) * 9;
#pragma unroll
    for (int co = 0; co < CO_T; ++co)
#pragma unroll
      for (int ky = 0; ky < 3; ++ky)
#pragma unroll
        for (int kx = 0; kx < 3; ++kx)
          acc[co] += (rv[ky] && cv[kx]) ? wsp[co * 9 + ky * 3 + kx] : 0.f;
  }

  for (int c0 = 0; c0 < CIN; c0 += CI_CH) {
    constexpr int TOTAL = CI_CH * LR * PW;
    for (int i = tid; i < TOTAL; i += 256) {
      int ci_l = i / (LR * PW);
      int rem = i % (LR * PW);
      int r = rem / PW, c = rem % PW;
      int ih = oh0 - 1 + r, iw = c - 1;
      int ci = c0 + ci_l;
      float v = 0.f;
      if ((unsigned)ih < (unsigned)H && (unsigned)iw < (unsigned)W) {
        if (ci < C1) v = in1[((long)(b * C1 + ci) * H + ih) * W + iw];
        else if (BCAST2) v = in2[b * C2 + ci - C1];
        else v = in2[((long)(b * C2 + ci - C1) * H + ih) * W + iw];
      }
      lds[i] = v;
    }
    __syncthreads();
#pragma unroll
    for (int ci_l = 0; ci_l < CI_CH; ++ci_l) {
      int ci = c0 + ci_l;
      float x[3][3];
#pragma unroll
      for (int ky = 0; ky < 3; ++ky)
#pragma unroll
        for (int kx = 0; kx < 3; ++kx)
          x[ky][kx] = lds[ci_l * (LR * PW) + (ty + ky) * PW + tx + kx];
      const float* wb = w + (long)ci * 9;
#pragma unroll
      for (int co = 0; co < CO_T; ++co) {
        const float* wp = wb + (long)(co0 + co) * CIN_W * 9;
#pragma unroll
        for (int ky = 0; ky < 3; ++ky)
#pragma unroll
          for (int kx = 0; kx < 3; ++kx)
            acc[co] += wp[ky * 3 + kx] * x[ky][kx];
      }
    }
    __syncthreads();
  }

#pragma unroll
  for (int co = 0; co < CO_T; ++co) {
    float a = acc[co];
    if (RELU) a = fmaxf(a, 0.f);
    if (MIX) {
      float m = in1[((long)(b * C1 + co0 + co) * H + oh) * W + tx];
      a = 0.99f * m + 0.01f * a;
    }
    out[((long)(b * COUT + co0 + co) * H + oh) * W + tx] = a;
  }
}

// ============== conv4x4 s2 p1 + relu, w_s in LDS, dbuf chunk pipeline =======
template<int CIN, int CI_CH, int COUT, int CO_T, int WIN, int HIN, int TW, int TH>
__global__ __launch_bounds__(256) void k_c4(
    const float* __restrict__ in, const float* __restrict__ w,
    const float* __restrict__ bias, float* __restrict__ out)
{
  constexpr int Wo = WIN / 2, Ho = HIN / 2;
  constexpr int PW = 2 * TW + 4;
  constexpr int LR = 2 * TH + 2;
  constexpr int TOTAL = CI_CH * LR * PW;
  constexpr int SITER = (TOTAL + 255) / 256;
  constexpr int WTOT = CIN * CO_T * 16;
  __shared__ float lin[2][TOTAL];
  __shared__ float w_s[WTOT];

  int tid = threadIdx.x;
  int tx = tid % TW, ty = tid / TW;
  int b = blockIdx.y;
  int co0 = blockIdx.z * CO_T;
  int oh0 = blockIdx.x * TH;
  int oh = oh0 + ty;
  int R0 = 2 * oh0 - 1;

  // stage weights once: w_s[ci][co][t]
  for (int i = tid; i < WTOT; i += 256) {
    int t = i & 15, co = (i >> 4) % CO_T, ci = (i >> 4) / CO_T;
    w_s[i] = w[((long)(co0 + co) * CIN + ci) * 16 + t];
  }

  float acc[CO_T];
#pragma unroll
  for (int i = 0; i < CO_T; ++i) acc[i] = bias[co0 + i];

  float sreg[SITER];
  // prologue: load + write chunk 0
#pragma unroll
  for (int it = 0; it < SITER; ++it) {
    int i = tid + it * 256;
    float v = 0.f;
    if (i < TOTAL) {
      int ci_l = i / (LR * PW);
      int rem = i % (LR * PW);
      int r = rem / PW, c = rem % PW;
      int ih = R0 + r, iw = c - 1;
      if ((unsigned)ih < (unsigned)HIN && (unsigned)iw < (unsigned)WIN)
        v = in[((long)(b * CIN + ci_l) * HIN + ih) * WIN + iw];
    }
    sreg[it] = v;
  }
#pragma unroll
  for (int it = 0; it < SITER; ++it) {
    int i = tid + it * 256;
    if (i < TOTAL) lin[0][i] = sreg[it];
  }

  int cur = 0;
  for (int c0 = 0; c0 < CIN; c0 += CI_CH) {
    bool has_next = (c0 + CI_CH < CIN);
    if (has_next) {
#pragma unroll
      for (int it = 0; it < SITER; ++it) {
        int i = tid + it * 256;
        float v = 0.f;
        if (i < TOTAL) {
          int ci_l = i / (LR * PW);
          int rem = i % (LR * PW);
          int r = rem / PW, c = rem % PW;
          int ih = R0 + r, iw = c - 1;
          if ((unsigned)ih < (unsigned)HIN && (unsigned)iw < (unsigned)WIN)
            v = in[((long)(b * CIN + c0 + CI_CH + ci_l) * HIN + ih) * WIN + iw];
        }
        sreg[it] = v;
      }
    }
    __syncthreads();   // lin[cur] ready
#pragma unroll
    for (int ci_l = 0; ci_l < CI_CH; ++ci_l) {
      int ci = c0 + ci_l;
      float x[4][4];
#pragma unroll
      for (int ky = 0; ky < 4; ++ky)
#pragma unroll
        for (int kx = 0; kx < 4; ++kx)
          x[ky][kx] = lin[cur][ci_l * (LR * PW) + (2 * ty + ky) * PW + 2 * tx + kx];
#pragma unroll
      for (int co = 0; co < CO_T; ++co) {
        const float* wp = &w_s[(ci * CO_T + co) * 16];
        float4 wa = *(const float4*)(wp);
        float4 wb = *(const float4*)(wp + 4);
        float4 wc = *(const float4*)(wp + 8);
        float4 wd = *(const float4*)(wp + 12);
        acc[co] += wa.x*x[0][0] + wa.y*x[0][1] + wa.z*x[0][2] + wa.w*x[0][3]
                 + wb.x*x[1][0] + wb.y*x[1][1] + wb.z*x[1][2] + wb.w*x[1][3]
                 + wc.x*x[2][0] + wc.y*x[2][1] + wc.z*x[2][2] + wc.w*x[2][3]
                 + wd.x*x[3][0] + wd.y*x[3][1] + wd.z*x[3][2] + wd.w*x[3][3];
      }
    }
    if (has_next) {
#pragma unroll
      for (int it = 0; it < SITER; ++it) {
        int i = tid + it * 256;
        if (i < TOTAL) lin[cur ^ 1][i] = sreg[it];
      }
    }
    cur ^= 1;
  }

#pragma unroll
  for (int co = 0; co < CO_T; ++co)
    out[((long)(b * COUT + co0 + co) * Ho + oh) * Wo + tx] = fmaxf(acc[co], 0.f);
}

// ============== convT 4x4 s2 p1 + relu, w_s in LDS, dbuf pipeline ===========
// weight [Cin][Cout][4][4]
template<int C1, int C2, int COUT, int CO_T, int WIN, int HIN, int TPR, int CI_CH>
__global__ __launch_bounds__(256) void k_ct(
    const float* __restrict__ in1, const float* __restrict__ in2,
    const float* __restrict__ w, const float* __restrict__ bias,
    float* __restrict__ out)
{
  constexpr int CIN = C1 + C2;
  constexpr int Wo = 2 * WIN, Ho = 2 * HIN;
  constexpr int PW = WIN + 4;
  constexpr int LR = TPR + 2;
  constexpr int TOTAL = CI_CH * LR * PW;
  constexpr int SITER = (TOTAL + 255) / 256;
  constexpr int WTOT = CIN * CO_T * 16;
  __shared__ float lin[2][TOTAL];
  __shared__ float w_s[WTOT];

  int tid = threadIdx.x;
  int s = tid % WIN, dt = tid / WIN;
  int b = blockIdx.y;
  int co0 = blockIdx.z * CO_T;
  int t0 = blockIdx.x * TPR;
  int t = t0 + dt;

  // stage weights once: w_s[ci][co][t]
  for (int i = tid; i < WTOT; i += 256) {
    int tt = i & 15, co = (i >> 4) % CO_T, ci = (i >> 4) / CO_T;
    w_s[i] = w[((long)ci * COUT + co0 + co) * 16 + tt];
  }

  float aee[CO_T], aeo[CO_T], aoe[CO_T], aoo[CO_T];
#pragma unroll
  for (int i = 0; i < CO_T; ++i) {
    float bb = bias[co0 + i];
    aee[i] = bb; aeo[i] = bb; aoe[i] = bb; aoo[i] = bb;
  }

  float sreg[SITER];
#pragma unroll
  for (int it = 0; it < SITER; ++it) {
    int i = tid + it * 256;
    float v = 0.f;
    if (i < TOTAL) {
      int ci_l = i / (LR * PW);
      int rem = i % (LR * PW);
      int r = rem / PW, c = rem % PW;
      int ih = t0 - 1 + r, iw = c - 1;
      if ((unsigned)ih < (unsigned)HIN && (unsigned)iw < (unsigned)WIN) {
        v = (ci_l < C1) ? in1[((long)(b * C1 + ci_l) * HIN + ih) * WIN + iw]
                        : in2[((long)(b * C2 + ci_l - C1) * HIN + ih) * WIN + iw];
      }
    }
    sreg[it] = v;
  }
#pragma unroll
  for (int it = 0; it < SITER; ++it) {
    int i = tid + it * 256;
    if (i < TOTAL) lin[0][i] = sreg[it];
  }

  int cur = 0;
  for (int c0 = 0; c0 < CIN; c0 += CI_CH) {
    bool has_next = (c0 + CI_CH < CIN);
    if (has_next) {
#pragma unroll
      for (int it = 0; it < SITER; ++it) {
        int i = tid + it * 256;
        float v = 0.f;
        if (i < TOTAL) {
          int ci_l = i / (LR * PW);
          int rem = i % (LR * PW);
          int r = rem / PW, c = rem % PW;
          int ih = t0 - 1 + r, iw = c - 1;
          int ci = c0 + CI_CH + ci_l;
          if ((unsigned)ih < (unsigned)HIN && (unsigned)iw < (unsigned)WIN) {
            v = (ci < C1) ? in1[((long)(b * C1 + ci) * HIN + ih) * WIN + iw]
                          : in2[((long)(b * C2 + ci - C1) * HIN + ih) * WIN + iw];
          }
        }
        sreg[it] = v;
      }
    }
    __syncthreads();   // lin[cur] ready
#pragma unroll
    for (int ci_l = 0; ci_l < CI_CH; ++ci_l) {
      int ci = c0 + ci_l;
      float x[3][3];   // rows t-1,t,t+1 ; cols s-1,s,s+1
#pragma unroll
      for (int r = 0; r < 3; ++r)
#pragma unroll
        for (int c = 0; c < 3; ++c)
          x[r][c] = lin[cur][ci_l * (LR * PW) + (dt + r) * PW + s + c];
#pragma unroll
      for (int co = 0; co < CO_T; ++co) {
        const float* wp = &w_s[(ci * CO_T + co) * 16];
        float4 wa = *(const float4*)(wp);        // w00..w03
        float4 wb = *(const float4*)(wp + 4);    // w10..w13
        float4 wc = *(const float4*)(wp + 8);    // w20..w23
        float4 wd = *(const float4*)(wp + 12);   // w30..w33
        aee[co] += wb.y * x[1][1] + wb.w * x[1][0] + wd.y * x[0][1] + wd.w * x[0][0];
        aeo[co] += wb.x * x[1][2] + wb.z * x[1][1] + wd.x * x[0][2] + wd.z * x[0][1];
        aoe[co] += wa.y * x[2][1] + wa.w * x[2][0] + wc.y * x[1][1] + wc.w * x[1][0];
        aoo[co] += wa.x * x[2][2] + wa.z * x[2][1] + wc.x * x[1][2] + wc.z * x[1][1];
      }
    }
    if (has_next) {
#pragma unroll
      for (int it = 0; it < SITER; ++it) {
        int i = tid + it * 256;
        if (i < TOTAL) lin[cur ^ 1][i] = sreg[it];
      }
    }
    cur ^= 1;
  }

#pragma unroll
  for (int co = 0; co < CO_T; ++co) {
    long base = ((long)(b * COUT + co0 + co) * Ho + 2 * t) * Wo + 2 * s;
    float2 r0; r0.x = fmaxf(aee[co], 0.f); r0.y = fmaxf(aeo[co], 0.f);
    float2 r1; r1.x = fmaxf(aoe[co], 0.f); r1.y = fmaxf(aoo[co], 0.f);
    *(float2*)(out + base) = r0;
    *(float2*)(out + base + Wo) = r1;
  }
}

// ============== wsum precompute for style-merge broadcast channels ==========
__global__ __launch_bounds__(256) void k_wsum(
    const float* __restrict__ w, const float* __restrict__ sf,
    float* __restrict__ wsum)
{
  int b = blockIdx.x;
  for (int i = threadIdx.x; i < 576; i += 256) {
    int co = i / 9, t = i % 9;
    float s = 0.f;
    for (int ci = 0; ci < 64; ++ci)
      s += w[((long)co * 128 + 64 + ci) * 9 + t] * sf[b * 64 + ci];
    wsum[((long)b * 64 + co) * 9 + t] = s;
  }
}

// ============== q/k projection -> qT [B][N][8], kC [B][8][N] ================
__global__ __launch_bounds__(256) void k_qkproj(
    const float* __restrict__ x, const float* __restrict__ wq,
    const float* __restrict__ bq, const float* __restrict__ wk,
    const float* __restrict__ bk, float* __restrict__ qT,
    float* __restrict__ kC, int N)
{
  int idx = blockIdx.x * 256 + threadIdx.x;
  int n = idx % N, b = idx / N;
  float qa[8], ka[8];
#pragma unroll
  for (int c = 0; c < 8; ++c) { qa[c] = bq[c]; ka[c] = bk[c]; }
  const float* src = x + (long)b * 64 * N + n;
  for (int ci = 0; ci < 64; ++ci) {
    float xv = src[(long)ci * N];
#pragma unroll
    for (int c = 0; c < 8; ++c) {
      qa[c] += wq[c * 64 + ci] * xv;
      ka[c] += wk[c * 64 + ci] * xv;
    }
  }
  float* qo = qT + ((long)b * N + n) * 8;
#pragma unroll
  for (int c = 0; c < 8; ++c) qo[c] = qa[c];
#pragma unroll
  for (int c = 0; c < 8; ++c) kC[((long)b * 8 + c) * N + n] = ka[c];
}

// ============== V projection -> vT [B][N][64], c-quarter split ==============
__global__ __launch_bounds__(256) void k_vprojT(
    const float* __restrict__ x, const float* __restrict__ w,
    const float* __restrict__ bias, float* __restrict__ vT, int N)
{
  int idx = blockIdx.x * 256 + threadIdx.x;
  int cq = blockIdx.y * 16;
  int n = idx % N, b = idx / N;
  float va[16];
#pragma unroll
  for (int c = 0; c < 16; ++c) va[c] = bias[cq + c];
  const float* src = x + (long)b * 64 * N + n;
  for (int ci = 0; ci < 64; ++ci) {
    float xv = src[(long)ci * N];
#pragma unroll
    for (int c = 0; c < 16; ++c) va[c] += w[(cq + c) * 64 + ci] * xv;
  }
  float* vo = vT + ((long)b * N + n) * 64 + cq;
#pragma unroll
  for (int c = 0; c < 16; c += 4) {
    float4 o; o.x = va[c]; o.y = va[c+1]; o.z = va[c+2]; o.w = va[c+3];
    *(float4*)(vo + c) = o;
  }
}

// ============== flash attention v2: TQ=64, 4q x 4c register tile ============
__global__ __launch_bounds__(256) void k_fattn(
    const float* __restrict__ qT, const float* __restrict__ kC,
    const float* __restrict__ vT, const float* __restrict__ xb,
    const float* __restrict__ gamma_p, float* __restrict__ outb, int N)
{
  __shared__ float k_s[8][68];
  __shared__ float v_s[64 * 64];   // [m][c]
  __shared__ float p_s[64][68];    // [m][q]; reused as o_s[c][q]

  int tid = threadIdx.x;
  int b = blockIdx.x >> 6;
  int n0 = (blockIdx.x & 63) * 64;
  int qg = tid >> 4;
  int xg = tid & 15;

  float qv[4][8];
#pragma unroll
  for (int i = 0; i < 4; ++i) {
    const float4* qp = (const float4*)(qT + ((long)b * N + n0 + qg * 4 + i) * 8);
    float4 a = qp[0], c = qp[1];
    qv[i][0]=a.x; qv[i][1]=a.y; qv[i][2]=a.z; qv[i][3]=a.w;
    qv[i][4]=c.x; qv[i][5]=c.y; qv[i][6]=c.z; qv[i][7]=c.w;
  }

  float o[4][4];
#pragma unroll
  for (int i = 0; i < 4; ++i)
#pragma unroll
    for (int j = 0; j < 4; ++j) o[i][j] = 0.f;
  float l[4] = {0.f, 0.f, 0.f, 0.f};

  const float* kbase = kC + (long)b * 8 * N;
  const float* vbase = vT + (long)b * N * 64;

  for (int t = 0; t < 64; ++t) {
    int m0 = t * 64;
    float4 vr0, vr1, vr2, vr3;
    {
      const float4* vp = (const float4*)(vbase + (long)m0 * 64) + tid;
      vr0 = vp[0]; vr1 = vp[256]; vr2 = vp[512]; vr3 = vp[768];
    }
    {
      int kk = tid >> 5, seg = tid & 31;
      float2 kv2 = *(const float2*)(kbase + (long)kk * N + m0 + seg * 2);
      *(float2*)&k_s[kk][seg * 2] = kv2;
    }
    __syncthreads();

    float s0[4], s1[4], s2[4], s3[4];
#pragma unroll
    for (int i = 0; i < 4; ++i) { s0[i]=0.f; s1[i]=0.f; s2[i]=0.f; s3[i]=0.f; }
#pragma unroll
    for (int kk = 0; kk < 8; ++kk) {
      float4 kx = *(const float4*)&k_s[kk][xg * 4];
#pragma unroll
      for (int i = 0; i < 4; ++i) {
        float q = qv[i][kk];
        s0[i] += q * kx.x; s1[i] += q * kx.y; s2[i] += q * kx.z; s3[i] += q * kx.w;
      }
    }
    float p0[4], p1[4], p2[4], p3[4];
#pragma unroll
    for (int i = 0; i < 4; ++i) {
      p0[i] = __expf(s0[i]); p1[i] = __expf(s1[i]);
      p2[i] = __expf(s2[i]); p3[i] = __expf(s3[i]);
      l[i] += p0[i] + p1[i] + p2[i] + p3[i];
    }
    {
      float4 w0; w0.x=p0[0]; w0.y=p0[1]; w0.z=p0[2]; w0.w=p0[3];
      float4 w1; w1.x=p1[0]; w1.y=p1[1]; w1.z=p1[2]; w1.w=p1[3];
      float4 w2; w2.x=p2[0]; w2.y=p2[1]; w2.z=p2[2]; w2.w=p2[3];
      float4 w3; w3.x=p3[0]; w3.y=p3[1]; w3.z=p3[2]; w3.w=p3[3];
      *(float4*)&p_s[xg * 4 + 0][qg * 4] = w0;
      *(float4*)&p_s[xg * 4 + 1][qg * 4] = w1;
      *(float4*)&p_s[xg * 4 + 2][qg * 4] = w2;
      *(float4*)&p_s[xg * 4 + 3][qg * 4] = w3;
    }
    {
      float* vd = v_s + tid * 4;
      *(float4*)(vd +    0) = vr0;
      *(float4*)(vd + 1024) = vr1;
      *(float4*)(vd + 2048) = vr2;
      *(float4*)(vd + 3072) = vr3;
    }
    __syncthreads();

#pragma unroll 2
    for (int mm = 0; mm < 16; ++mm) {
#pragma unroll
      for (int j = 0; j < 4; ++j) {
        int m = mm * 4 + j;
        float4 pj = *(const float4*)&p_s[m][qg * 4];
        float4 vj = *(const float4*)&v_s[m * 64 + xg * 4];
        o[0][0] += pj.x * vj.x; o[0][1] += pj.x * vj.y; o[0][2] += pj.x * vj.z; o[0][3] += pj.x * vj.w;
        o[1][0] += pj.y * vj.x; o[1][1] += pj.y * vj.y; o[1][2] += pj.y * vj.z; o[1][3] += pj.y * vj.w;
        o[2][0] += pj.z * vj.x; o[2][1] += pj.z * vj.y; o[2][2] += pj.z * vj.z; o[2][3] += pj.z * vj.w;
        o[3][0] += pj.w * vj.x; o[3][1] += pj.w * vj.y; o[3][2] += pj.w * vj.z; o[3][3] += pj.w * vj.w;
      }
    }
    __syncthreads();
  }

#pragma unroll
  for (int i = 0; i < 4; ++i) {
#pragma unroll
    for (int d = 1; d < 16; d <<= 1) l[i] += __shfl_xor(l[i], d);
  }
  float g = gamma_p[0];
  float inv[4];
#pragma unroll
  for (int i = 0; i < 4; ++i) inv[i] = g / l[i];

#pragma unroll
  for (int j = 0; j < 4; ++j) {
    float4 w4;
    w4.x = o[0][j] * inv[0]; w4.y = o[1][j] * inv[1];
    w4.z = o[2][j] * inv[2]; w4.w = o[3][j] * inv[3];
    *(float4*)&p_s[xg * 4 + j][qg * 4] = w4;
  }
  __syncthreads();
  for (int idx = tid; idx < 4096; idx += 256) {
    int c = idx >> 6, q = idx & 63;
    long off = ((long)b * 64 + c) * N + n0 + q;
    outb[off] = p_s[c][q] + xb[off];
  }
}

// ================= adaptive avg pool to 8x8 ================================
__global__ __launch_bounds__(256) void k_pool8(
    const float* __restrict__ in, float* __restrict__ out, int B, int C, int H, int W)
{
  int idx = blockIdx.x * 256 + threadIdx.x;
  int total = B * C * 64;
  if (idx >= total) return;
  int ow = idx & 7, oh = (idx >> 3) & 7;
  int c = (idx >> 6) % C, b = idx / (64 * C);
  int bh = H / 8, bw = W / 8;
  const float* src = in + ((long)(b * C + c)) * H * W;
  float s = 0.f;
  for (int y = 0; y < bh; ++y)
    for (int x = 0; x < bw; ++x)
      s += src[(oh * bh + y) * W + ow * bw + x];
  out[idx] = s / (float)(bh * bw);
}

// ================= fc + relu (wave per output) ==============================
__global__ __launch_bounds__(256) void k_fc_relu(
    const float* __restrict__ in, const float* __restrict__ w,
    const float* __restrict__ bias, float* __restrict__ out, int B, int K, int O)
{
  int gi = blockIdx.x * 4 + (threadIdx.x >> 6);
  int lane = threadIdx.x & 63;
  if (gi >= B * O) return;
  int b = gi / O, o = gi % O;
  const float* x = in + (long)b * K;
  const float* wp = w + (long)o * K;
  float s = 0.f;
  for (int i = lane; i < K; i += 64) s += x[i] * wp[i];
#pragma unroll
  for (int d = 1; d < 64; d <<= 1) s += __shfl_xor(s, d);
  if (lane == 0) out[gi] = fmaxf(s + bias[o], 0.f);
}

// ================= line filter: per-row std -> sigmoid mask =================
__global__ __launch_bounds__(256) void k_lf_rowstat(
    const float* __restrict__ x, float* __restrict__ mask_raw, int rows, int W)
{
  int row = blockIdx.x * 4 + (threadIdx.x >> 6);
  int lane = threadIdx.x & 63;
  if (row >= rows) return;
  const float* p = x + (long)row * W;
  float s = 0.f;
  for (int i = lane; i < W; i += 64) s += p[i];
#pragma unroll
  for (int d = 1; d < 64; d <<= 1) s += __shfl_xor(s, d);
  float mean = s / (float)W;
  float v = 0.f;
  for (int i = lane; i < W; i += 64) { float t = p[i] - mean; v += t * t; }
#pragma unroll
  for (int d = 1; d < 64; d <<= 1) v += __shfl_xor(v, d);
  float stdv = sqrtf(v / (float)(W - 1));
  float mask = 1.f / (1.f + __expf(-(0.05f - stdv) * 10.f));
  if (lane == 0) mask_raw[row] = mask;
}

// ================= line filter apply (+optional tanh) =======================
__global__ __launch_bounds__(256) void k_lf_apply(
    const float* __restrict__ x, const float* __restrict__ mask_raw,
    float* __restrict__ out, int BC, int H, int W, float strength, int do_tanh)
{
  long idx = (long)blockIdx.x * 256 + threadIdx.x;
  long total = (long)BC * H * W;
  if (idx >= total) return;
  int wcol = (int)(idx % W);
  int h = (int)((idx / W) % H);
  int bc = (int)(idx / ((long)W * H));
  const float* px = x + (long)bc * H * W;
  const float* pm = mask_raw + (long)bc * H;
  float vs = 0.f, mb = 0.f;
#pragma unroll
  for (int d = -2; d <= 2; ++d) {
    int hh = h + d; hh = hh < 0 ? 0 : (hh >= H ? H - 1 : hh);
    vs += px[hh * W + wcol];
    mb += pm[hh];
  }
  vs *= 0.2f; mb *= 0.2f;
  float m = mb * strength;
  float o = x[idx] * (1.f - m) + vs * m;
  if (do_tanh) o = tanhf(o);
  out[idx] = o;
}

// ---------------- launch ----------------
static inline unsigned gdiv(long total) { return (unsigned)((total + 255) / 256); }

extern "C" void kernel_launch(void* const* d_in, const int* in_sizes, int n_in,
                              void* d_out, int out_size, void* d_ws, size_t ws_size,
                              hipStream_t stream)
{
  (void)in_sizes; (void)n_in; (void)out_size; (void)ws_size;
  const float* sketch   = (const float*)d_in[0];
  const float* depth    = (const float*)d_in[1];
  const float* style    = (const float*)d_in[2];
  const float* enc1_w   = (const float*)d_in[3];
  const float* enc1_b   = (const float*)d_in[4];
  const float* enc2_w   = (const float*)d_in[5];
  const float* enc2_b   = (const float*)d_in[6];
  const float* enc3_w   = (const float*)d_in[7];
  const float* enc3_b   = (const float*)d_in[8];
  const float* se1_w    = (const float*)d_in[9];
  const float* se1_b    = (const float*)d_in[10];
  const float* se2_w    = (const float*)d_in[11];
  const float* se2_b    = (const float*)d_in[12];
  const float* se3_w    = (const float*)d_in[13];
  const float* se3_b    = (const float*)d_in[14];
  const float* sp1_w    = (const float*)d_in[15];
  const float* sp1_b    = (const float*)d_in[16];
  const float* sp2_w    = (const float*)d_in[17];
  const float* sp2_b    = (const float*)d_in[18];
  const float* sm_w     = (const float*)d_in[19];
  const float* sm_b     = (const float*)d_in[20];
  const float* attn_q_w = (const float*)d_in[21];
  const float* attn_q_b = (const float*)d_in[22];
  const float* attn_k_w = (const float*)d_in[23];
  const float* attn_k_b = (const float*)d_in[24];
  const float* attn_v_w = (const float*)d_in[25];
  const float* attn_v_b = (const float*)d_in[26];
  const float* attn_g   = (const float*)d_in[27];
  const float* bn_w     = (const float*)d_in[28];
  const float* bn_b     = (const float*)d_in[29];
  const float* dec3_w   = (const float*)d_in[30];
  const float* dec3_b   = (const float*)d_in[31];
  const float* dec2_w   = (const float*)d_in[32];
  const float* dec2_b   = (const float*)d_in[33];
  const float* dec1_w   = (const float*)d_in[34];
  const float* dec1_b   = (const float*)d_in[35];
  float* out = (float*)d_out;

  float* ws    = (float*)d_ws;
  float* e1    = ws + OFF_E1;
  float* e2    = ws + OFF_E2;
  float* e3a   = ws + OFF_E3A;
  float* e3b   = ws + OFF_E3B;
  float* big16 = ws + OFF_BIG16;
  float* big8  = ws + OFF_BIG8;
  float* b4    = ws + OFF_B4;
  float* vbuf  = ws + OFF_V;
  float* qbuf  = ws + OFF_Q;
  float* kbuf  = ws + OFF_K;
  float* pool  = ws + OFF_POOL;
  float* sf1   = ws + OFF_SF1;
  float* sf2   = ws + OFF_SF2;
  float* rowst = ws + OFF_ROW;
  float* d2lf  = ws + OFF_D2LF;
  float* pre   = ws + OFF_PRE;

  const int B = 4;

  // ---- encoder ----
  k_c3<1,1,0, 2, 256,256,1, 2, 16,16, 1,0,0><<<dim3(256, B, 1), 256, 0, stream>>>(
      sketch, depth, enc1_w, enc1_b, nullptr, e1);
  k_c4<16,2,32,8, 256,256, 128,2><<<dim3(64, B, 4), 256, 0, stream>>>(e1, enc2_w, enc2_b, e2);
  k_c4<32,2,64,4, 128,128, 64,4><<<dim3(16, B, 16), 256, 0, stream>>>(e2, enc3_w, enc3_b, e3a);
  k_lf_rowstat<<<(B*64*64 + 3)/4, 256, 0, stream>>>(e3a, rowst, B*64*64, 64);
  k_lf_apply<<<gdiv((long)B*64*64*64), 256, 0, stream>>>(e3a, rowst, e3b, B*64, 64, 64, 0.8f, 0);

  // ---- style branch ----
  k_c3<3,0,0, 3, 256,256,1, 3, 16,16, 1,0,0><<<dim3(256, B, 1), 256, 0, stream>>>(
      style, nullptr, se1_w, se1_b, nullptr, big16);
  k_c4<16,2,32,8, 256,256, 128,2><<<dim3(64, B, 4), 256, 0, stream>>>(big16, se2_w, se2_b, big8);
  k_c4<32,2,64,4, 128,128, 64,4><<<dim3(16, B, 16), 256, 0, stream>>>(big8, se3_w, se3_b, b4);
  k_pool8<<<gdiv(B*64*64), 256, 0, stream>>>(b4, pool, B, 64, 64, 64);
  k_fc_relu<<<(B*64 + 3)/4, 256, 0, stream>>>(pool, sp1_w, sp1_b, sf1, B, 4096, 64);
  k_fc_relu<<<(B*64 + 3)/4, 256, 0, stream>>>(sf1, sp2_w, sp2_b, sf2, B, 64, 64);

  // ---- style merge (+mix fused, bcast channels via wsum) ----
  k_wsum<<<B, 256, 0, stream>>>(sm_w, sf2, pool);
  k_c3<64,0,0, 128, 64,64,4, 8, 64,4, 1,1,1><<<dim3(16, B, 16), 256, 0, stream>>>(
      e3b, nullptr, sm_w, sm_b, pool, e3a);

  // ---- self-attention on e3a -> e3b ----
  k_qkproj<<<64, 256, 0, stream>>>(e3a, attn_q_w, attn_q_b, attn_k_w, attn_k_b, qbuf, kbuf, 4096);
  k_vprojT<<<dim3(64, 4), 256, 0, stream>>>(e3a, attn_v_w, attn_v_b, vbuf, 4096);
  k_fattn<<<B * 64, 256, 0, stream>>>(qbuf, kbuf, vbuf, e3a, attn_g, e3b, 4096);

  // ---- bottleneck + decoder ----
  k_c3<64,0,0, 64, 64,64,4, 8, 64,4, 1,0,0><<<dim3(16, B, 16), 256, 0, stream>>>(
      e3b, nullptr, bn_w, bn_b, nullptr, b4);
  k_ct<64,64,32,2, 64,64, 4,4><<<dim3(16, B, 16), 256, 0, stream>>>(b4, e3b, dec3_w, dec3_b, big8);
  k_ct<32,32,16,4, 128,128, 2,4><<<dim3(64, B, 4), 256, 0, stream>>>(big8, e2, dec2_w, dec2_b, big16);
  k_lf_rowstat<<<(B*16*256 + 3)/4, 256, 0, stream>>>(big16, rowst, B*16*256, 256);
  k_lf_apply<<<gdiv((long)B*16*256*256), 256, 0, stream>>>(big16, rowst, d2lf, B*16, 256, 256, 0.8f, 0);
  k_c3<16,16,0, 32, 256,256,1, 8, 3,3, 0,0,0><<<dim3(256, B, 1), 256, 0, stream>>>(
      d2lf, e1, dec1_w, dec1_b, nullptr, pre);
  k_lf_rowstat<<<(B*3*256 + 3)/4, 256, 0, stream>>>(pre, rowst, B*3*256, 256);
  k_lf_apply<<<gdiv((long)B*3*256*256), 256, 0, stream>>>(pre, rowst, out, B*3, 256, 256, 0.9f, 1);
}

// Round 7
// 875.073 us; speedup vs baseline: 4.5700x; 1.0626x over previous
//
#include <hip/hip_runtime.h>
#include <cstdint>
#include <cstddef>

// ---------------- workspace layout (floats) ----------------
static const size_t OFF_E1    = 0;         // [4,16,256,256]
static const size_t OFF_E2    = 4194304;   // [4,32,128,128]
static const size_t OFF_E3A   = 6291456;   // [4,64,64,64]
static const size_t OFF_E3B   = 7340032;   // [4,64,64,64]
static const size_t OFF_BIG16 = 8388608;   // s1 | attn o_part [4][4][64][4096] | d2raw
static const size_t OFF_BIG8  = 12582912;  // s2 then d3
static const size_t OFF_B4    = 14680064;  // s3 then bn-out
static const size_t OFF_V     = 15728640;  // vT [4,4096,64]
static const size_t OFF_Q     = 16777216;  // qT [4,4096,8]
static const size_t OFF_K     = 16908288;  // kC [4,8,4096]
static const size_t OFF_POOL  = 17039360;  // pool then wsum[4][64][9]
static const size_t OFF_SF1   = 17055744;
static const size_t OFF_SF2   = 17056000;
static const size_t OFF_ROW   = 17056256;
static const size_t OFF_D2LF  = 17072640;  // attn l_part [4][4][4096] | then [4,16,256,256]
static const size_t OFF_PRE   = 21266944;  // [4,3,256,256]

// ============== conv3x3 s1 p1, LDS-staged, multi-co per thread ==============
template<int C1, int C2, int BCAST2, int CIN_W, int W, int H, int ROWS,
         int CI_CH, int COUT, int CO_T, int RELU, int MIX, int WSUM>
__global__ __launch_bounds__(256) void k_c3(
    const float* __restrict__ in1, const float* __restrict__ in2,
    const float* __restrict__ w, const float* __restrict__ bias,
    const float* __restrict__ wsum, float* __restrict__ out)
{
  constexpr int CIN = C1 + C2;
  constexpr int PW = W + 4;
  constexpr int LR = ROWS + 2;
  __shared__ float lds[CI_CH * LR * PW];

  int tid = threadIdx.x;
  int tx = tid % W, ty = tid / W;
  int b = blockIdx.y;
  int co0 = blockIdx.z * CO_T;
  int oh0 = blockIdx.x * ROWS;
  int oh = oh0 + ty;

  float acc[CO_T];
#pragma unroll
  for (int i = 0; i < CO_T; ++i) acc[i] = bias[co0 + i];

  if (WSUM) {
    bool rv0 = oh - 1 >= 0, rv2 = oh + 1 < H;
    bool cv0 = tx - 1 >= 0, cv2 = tx + 1 < W;
    bool rv[3] = {rv0, true, rv2};
    bool cv[3] = {cv0, true, cv2};
    const float* wsp = wsum + ((long)b * COUT + co0) * 9;
#pragma unroll
    for (int co = 0; co < CO_T; ++co)
#pragma unroll
      for (int ky = 0; ky < 3; ++ky)
#pragma unroll
        for (int kx = 0; kx < 3; ++kx)
          acc[co] += (rv[ky] && cv[kx]) ? wsp[co * 9 + ky * 3 + kx] : 0.f;
  }

  for (int c0 = 0; c0 < CIN; c0 += CI_CH) {
    constexpr int TOTAL = CI_CH * LR * PW;
    for (int i = tid; i < TOTAL; i += 256) {
      int ci_l = i / (LR * PW);
      int rem = i % (LR * PW);
      int r = rem / PW, c = rem % PW;
      int ih = oh0 - 1 + r, iw = c - 1;
      int ci = c0 + ci_l;
      float v = 0.f;
      if ((unsigned)ih < (unsigned)H && (unsigned)iw < (unsigned)W) {
        if (ci < C1) v = in1[((long)(b * C1 + ci) * H + ih) * W + iw];
        else if (BCAST2) v = in2[b * C2 + ci - C1];
        else v = in2[((long)(b * C2 + ci - C1) * H + ih) * W + iw];
      }
      lds[i] = v;
    }
    __syncthreads();
#pragma unroll
    for (int ci_l = 0; ci_l < CI_CH; ++ci_l) {
      int ci = c0 + ci_l;
      float x[3][3];
#pragma unroll
      for (int ky = 0; ky < 3; ++ky)
#pragma unroll
        for (int kx = 0; kx < 3; ++kx)
          x[ky][kx] = lds[ci_l * (LR * PW) + (ty + ky) * PW + tx + kx];
      const float* wb = w + (long)ci * 9;
#pragma unroll
      for (int co = 0; co < CO_T; ++co) {
        const float* wp = wb + (long)(co0 + co) * CIN_W * 9;
#pragma unroll
        for (int ky = 0; ky < 3; ++ky)
#pragma unroll
          for (int kx = 0; kx < 3; ++kx)
            acc[co] += wp[ky * 3 + kx] * x[ky][kx];
      }
    }
    __syncthreads();
  }

#pragma unroll
  for (int co = 0; co < CO_T; ++co) {
    float a = acc[co];
    if (RELU) a = fmaxf(a, 0.f);
    if (MIX) {
      float m = in1[((long)(b * C1 + co0 + co) * H + oh) * W + tx];
      a = 0.99f * m + 0.01f * a;
    }
    out[((long)(b * COUT + co0 + co) * H + oh) * W + tx] = a;
  }
}

// ============== conv4x4 s2 p1 + relu, w_s in LDS, dbuf chunk pipeline =======
template<int CIN, int CI_CH, int COUT, int CO_T, int WIN, int HIN, int TW, int TH>
__global__ __launch_bounds__(256) void k_c4(
    const float* __restrict__ in, const float* __restrict__ w,
    const float* __restrict__ bias, float* __restrict__ out)
{
  constexpr int Wo = WIN / 2, Ho = HIN / 2;
  constexpr int PW = 2 * TW + 4;
  constexpr int LR = 2 * TH + 2;
  constexpr int TOTAL = CI_CH * LR * PW;
  constexpr int SITER = (TOTAL + 255) / 256;
  constexpr int WTOT = CIN * CO_T * 16;
  __shared__ float lin[2][TOTAL];
  __shared__ float w_s[WTOT];

  int tid = threadIdx.x;
  int tx = tid % TW, ty = tid / TW;
  int b = blockIdx.y;
  int co0 = blockIdx.z * CO_T;
  int oh0 = blockIdx.x * TH;
  int oh = oh0 + ty;
  int R0 = 2 * oh0 - 1;

  for (int i = tid; i < WTOT; i += 256) {
    int t = i & 15, co = (i >> 4) % CO_T, ci = (i >> 4) / CO_T;
    w_s[i] = w[((long)(co0 + co) * CIN + ci) * 16 + t];
  }

  float acc[CO_T];
#pragma unroll
  for (int i = 0; i < CO_T; ++i) acc[i] = bias[co0 + i];

  float sreg[SITER];
#pragma unroll
  for (int it = 0; it < SITER; ++it) {
    int i = tid + it * 256;
    float v = 0.f;
    if (i < TOTAL) {
      int ci_l = i / (LR * PW);
      int rem = i % (LR * PW);
      int r = rem / PW, c = rem % PW;
      int ih = R0 + r, iw = c - 1;
      if ((unsigned)ih < (unsigned)HIN && (unsigned)iw < (unsigned)WIN)
        v = in[((long)(b * CIN + ci_l) * HIN + ih) * WIN + iw];
    }
    sreg[it] = v;
  }
#pragma unroll
  for (int it = 0; it < SITER; ++it) {
    int i = tid + it * 256;
    if (i < TOTAL) lin[0][i] = sreg[it];
  }

  int cur = 0;
  for (int c0 = 0; c0 < CIN; c0 += CI_CH) {
    bool has_next = (c0 + CI_CH < CIN);
    if (has_next) {
#pragma unroll
      for (int it = 0; it < SITER; ++it) {
        int i = tid + it * 256;
        float v = 0.f;
        if (i < TOTAL) {
          int ci_l = i / (LR * PW);
          int rem = i % (LR * PW);
          int r = rem / PW, c = rem % PW;
          int ih = R0 + r, iw = c - 1;
          if ((unsigned)ih < (unsigned)HIN && (unsigned)iw < (unsigned)WIN)
            v = in[((long)(b * CIN + c0 + CI_CH + ci_l) * HIN + ih) * WIN + iw];
        }
        sreg[it] = v;
      }
    }
    __syncthreads();
#pragma unroll
    for (int ci_l = 0; ci_l < CI_CH; ++ci_l) {
      int ci = c0 + ci_l;
      float x[4][4];
#pragma unroll
      for (int ky = 0; ky < 4; ++ky)
#pragma unroll
        for (int kx = 0; kx < 4; ++kx)
          x[ky][kx] = lin[cur][ci_l * (LR * PW) + (2 * ty + ky) * PW + 2 * tx + kx];
#pragma unroll
      for (int co = 0; co < CO_T; ++co) {
        const float* wp = &w_s[(ci * CO_T + co) * 16];
        float4 wa = *(const float4*)(wp);
        float4 wb = *(const float4*)(wp + 4);
        float4 wc = *(const float4*)(wp + 8);
        float4 wd = *(const float4*)(wp + 12);
        acc[co] += wa.x*x[0][0] + wa.y*x[0][1] + wa.z*x[0][2] + wa.w*x[0][3]
                 + wb.x*x[1][0] + wb.y*x[1][1] + wb.z*x[1][2] + wb.w*x[1][3]
                 + wc.x*x[2][0] + wc.y*x[2][1] + wc.z*x[2][2] + wc.w*x[2][3]
                 + wd.x*x[3][0] + wd.y*x[3][1] + wd.z*x[3][2] + wd.w*x[3][3];
      }
    }
    if (has_next) {
#pragma unroll
      for (int it = 0; it < SITER; ++it) {
        int i = tid + it * 256;
        if (i < TOTAL) lin[cur ^ 1][i] = sreg[it];
      }
    }
    cur ^= 1;
  }

#pragma unroll
  for (int co = 0; co < CO_T; ++co)
    out[((long)(b * COUT + co0 + co) * Ho + oh) * Wo + tx] = fmaxf(acc[co], 0.f);
}

// ============== convT 4x4 s2 p1 + relu, w_s in LDS, dbuf pipeline ===========
template<int C1, int C2, int COUT, int CO_T, int WIN, int HIN, int TPR, int CI_CH>
__global__ __launch_bounds__(256) void k_ct(
    const float* __restrict__ in1, const float* __restrict__ in2,
    const float* __restrict__ w, const float* __restrict__ bias,
    float* __restrict__ out)
{
  constexpr int CIN = C1 + C2;
  constexpr int Wo = 2 * WIN, Ho = 2 * HIN;
  constexpr int PW = WIN + 4;
  constexpr int LR = TPR + 2;
  constexpr int TOTAL = CI_CH * LR * PW;
  constexpr int SITER = (TOTAL + 255) / 256;
  constexpr int WTOT = CIN * CO_T * 16;
  __shared__ float lin[2][TOTAL];
  __shared__ float w_s[WTOT];

  int tid = threadIdx.x;
  int s = tid % WIN, dt = tid / WIN;
  int b = blockIdx.y;
  int co0 = blockIdx.z * CO_T;
  int t0 = blockIdx.x * TPR;
  int t = t0 + dt;

  for (int i = tid; i < WTOT; i += 256) {
    int tt = i & 15, co = (i >> 4) % CO_T, ci = (i >> 4) / CO_T;
    w_s[i] = w[((long)ci * COUT + co0 + co) * 16 + tt];
  }

  float aee[CO_T], aeo[CO_T], aoe[CO_T], aoo[CO_T];
#pragma unroll
  for (int i = 0; i < CO_T; ++i) {
    float bb = bias[co0 + i];
    aee[i] = bb; aeo[i] = bb; aoe[i] = bb; aoo[i] = bb;
  }

  float sreg[SITER];
#pragma unroll
  for (int it = 0; it < SITER; ++it) {
    int i = tid + it * 256;
    float v = 0.f;
    if (i < TOTAL) {
      int ci_l = i / (LR * PW);
      int rem = i % (LR * PW);
      int r = rem / PW, c = rem % PW;
      int ih = t0 - 1 + r, iw = c - 1;
      if ((unsigned)ih < (unsigned)HIN && (unsigned)iw < (unsigned)WIN) {
        v = (ci_l < C1) ? in1[((long)(b * C1 + ci_l) * HIN + ih) * WIN + iw]
                        : in2[((long)(b * C2 + ci_l - C1) * HIN + ih) * WIN + iw];
      }
    }
    sreg[it] = v;
  }
#pragma unroll
  for (int it = 0; it < SITER; ++it) {
    int i = tid + it * 256;
    if (i < TOTAL) lin[0][i] = sreg[it];
  }

  int cur = 0;
  for (int c0 = 0; c0 < CIN; c0 += CI_CH) {
    bool has_next = (c0 + CI_CH < CIN);
    if (has_next) {
#pragma unroll
      for (int it = 0; it < SITER; ++it) {
        int i = tid + it * 256;
        float v = 0.f;
        if (i < TOTAL) {
          int ci_l = i / (LR * PW);
          int rem = i % (LR * PW);
          int r = rem / PW, c = rem % PW;
          int ih = t0 - 1 + r, iw = c - 1;
          int ci = c0 + CI_CH + ci_l;
          if ((unsigned)ih < (unsigned)HIN && (unsigned)iw < (unsigned)WIN) {
            v = (ci < C1) ? in1[((long)(b * C1 + ci) * HIN + ih) * WIN + iw]
                          : in2[((long)(b * C2 + ci - C1) * HIN + ih) * WIN + iw];
          }
        }
        sreg[it] = v;
      }
    }
    __syncthreads();
#pragma unroll
    for (int ci_l = 0; ci_l < CI_CH; ++ci_l) {
      int ci = c0 + ci_l;
      float x[3][3];
#pragma unroll
      for (int r = 0; r < 3; ++r)
#pragma unroll
        for (int c = 0; c < 3; ++c)
          x[r][c] = lin[cur][ci_l * (LR * PW) + (dt + r) * PW + s + c];
#pragma unroll
      for (int co = 0; co < CO_T; ++co) {
        const float* wp = &w_s[(ci * CO_T + co) * 16];
        float4 wa = *(const float4*)(wp);
        float4 wb = *(const float4*)(wp + 4);
        float4 wc = *(const float4*)(wp + 8);
        float4 wd = *(const float4*)(wp + 12);
        aee[co] += wb.y * x[1][1] + wb.w * x[1][0] + wd.y * x[0][1] + wd.w * x[0][0];
        aeo[co] += wb.x * x[1][2] + wb.z * x[1][1] + wd.x * x[0][2] + wd.z * x[0][1];
        aoe[co] += wa.y * x[2][1] + wa.w * x[2][0] + wc.y * x[1][1] + wc.w * x[1][0];
        aoo[co] += wa.x * x[2][2] + wa.z * x[2][1] + wc.x * x[1][2] + wc.z * x[1][1];
      }
    }
    if (has_next) {
#pragma unroll
      for (int it = 0; it < SITER; ++it) {
        int i = tid + it * 256;
        if (i < TOTAL) lin[cur ^ 1][i] = sreg[it];
      }
    }
    cur ^= 1;
  }

#pragma unroll
  for (int co = 0; co < CO_T; ++co) {
    long base = ((long)(b * COUT + co0 + co) * Ho + 2 * t) * Wo + 2 * s;
    float2 r0; r0.x = fmaxf(aee[co], 0.f); r0.y = fmaxf(aeo[co], 0.f);
    float2 r1; r1.x = fmaxf(aoe[co], 0.f); r1.y = fmaxf(aoo[co], 0.f);
    *(float2*)(out + base) = r0;
    *(float2*)(out + base + Wo) = r1;
  }
}

// ============== wsum precompute for style-merge broadcast channels ==========
__global__ __launch_bounds__(256) void k_wsum(
    const float* __restrict__ w, const float* __restrict__ sf,
    float* __restrict__ wsum)
{
  int b = blockIdx.x;
  for (int i = threadIdx.x; i < 576; i += 256) {
    int co = i / 9, t = i % 9;
    float s = 0.f;
    for (int ci = 0; ci < 64; ++ci)
      s += w[((long)co * 128 + 64 + ci) * 9 + t] * sf[b * 64 + ci];
    wsum[((long)b * 64 + co) * 9 + t] = s;
  }
}

// ============== q/k projection -> qT [B][N][8], kC [B][8][N] ================
__global__ __launch_bounds__(256) void k_qkproj(
    const float* __restrict__ x, const float* __restrict__ wq,
    const float* __restrict__ bq, const float* __restrict__ wk,
    const float* __restrict__ bk, float* __restrict__ qT,
    float* __restrict__ kC, int N)
{
  int idx = blockIdx.x * 256 + threadIdx.x;
  int n = idx % N, b = idx / N;
  float qa[8], ka[8];
#pragma unroll
  for (int c = 0; c < 8; ++c) { qa[c] = bq[c]; ka[c] = bk[c]; }
  const float* src = x + (long)b * 64 * N + n;
  for (int ci = 0; ci < 64; ++ci) {
    float xv = src[(long)ci * N];
#pragma unroll
    for (int c = 0; c < 8; ++c) {
      qa[c] += wq[c * 64 + ci] * xv;
      ka[c] += wk[c * 64 + ci] * xv;
    }
  }
  float* qo = qT + ((long)b * N + n) * 8;
#pragma unroll
  for (int c = 0; c < 8; ++c) qo[c] = qa[c];
#pragma unroll
  for (int c = 0; c < 8; ++c) kC[((long)b * 8 + c) * N + n] = ka[c];
}

// ============== V projection -> vT [B][N][64], c-quarter split ==============
__global__ __launch_bounds__(256) void k_vprojT(
    const float* __restrict__ x, const float* __restrict__ w,
    const float* __restrict__ bias, float* __restrict__ vT, int N)
{
  int idx = blockIdx.x * 256 + threadIdx.x;
  int cq = blockIdx.y * 16;
  int n = idx % N, b = idx / N;
  float va[16];
#pragma unroll
  for (int c = 0; c < 16; ++c) va[c] = bias[cq + c];
  const float* src = x + (long)b * 64 * N + n;
  for (int ci = 0; ci < 64; ++ci) {
    float xv = src[(long)ci * N];
#pragma unroll
    for (int c = 0; c < 16; ++c) va[c] += w[(cq + c) * 64 + ci] * xv;
  }
  float* vo = vT + ((long)b * N + n) * 64 + cq;
#pragma unroll
  for (int c = 0; c < 16; c += 4) {
    float4 o; o.x = va[c]; o.y = va[c+1]; o.z = va[c+2]; o.w = va[c+3];
    *(float4*)(vo + c) = o;
  }
}

// ============== flash attention v3: KV-split x4, P [q][m], partials =========
// grid (64 n0-tiles, B, 4 splits); 256 thr: qg = tid>>4 (4 q), xg = tid&15
// (4 m in QK / 4 c in PV). No-max softmax => partials are purely additive.
__global__ __launch_bounds__(256) void k_fattn(
    const float* __restrict__ qT, const float* __restrict__ kC,
    const float* __restrict__ vT, float* __restrict__ o_part,
    float* __restrict__ l_part, int N)
{
  __shared__ float k_s[8][68];
  __shared__ float v_s[64 * 64];   // [m][c]
  __shared__ float p_s[64][68];    // [q][m]; reused as o_s[c][q]

  int tid = threadIdx.x;
  int n0 = blockIdx.x * 64;
  int b = blockIdx.y;
  int split = blockIdx.z;
  int qg = tid >> 4;
  int xg = tid & 15;

  float qv[4][8];
#pragma unroll
  for (int i = 0; i < 4; ++i) {
    const float4* qp = (const float4*)(qT + ((long)b * N + n0 + qg * 4 + i) * 8);
    float4 a = qp[0], c = qp[1];
    qv[i][0]=a.x; qv[i][1]=a.y; qv[i][2]=a.z; qv[i][3]=a.w;
    qv[i][4]=c.x; qv[i][5]=c.y; qv[i][6]=c.z; qv[i][7]=c.w;
  }

  float o[4][4];
#pragma unroll
  for (int i = 0; i < 4; ++i)
#pragma unroll
    for (int j = 0; j < 4; ++j) o[i][j] = 0.f;
  float l[4] = {0.f, 0.f, 0.f, 0.f};

  const float* kbase = kC + (long)b * 8 * N;
  const float* vbase = vT + (long)b * N * 64;

  for (int t = split * 16; t < split * 16 + 16; ++t) {
    int m0 = t * 64;
    float4 vr0, vr1, vr2, vr3;
    {
      const float4* vp = (const float4*)(vbase + (long)m0 * 64) + tid;
      vr0 = vp[0]; vr1 = vp[256]; vr2 = vp[512]; vr3 = vp[768];
    }
    {
      int kk = tid >> 5, seg = tid & 31;
      float2 kv2 = *(const float2*)(kbase + (long)kk * N + m0 + seg * 2);
      *(float2*)&k_s[kk][seg * 2] = kv2;
    }
    __syncthreads();   // k_s ready; prev-tile p_s/v_s consumed

    // QK^T: s[i = q][j = m] for m = xg*4..+3
    float s0[4], s1[4], s2[4], s3[4];
#pragma unroll
    for (int i = 0; i < 4; ++i) { s0[i]=0.f; s1[i]=0.f; s2[i]=0.f; s3[i]=0.f; }
#pragma unroll
    for (int kk = 0; kk < 8; ++kk) {
      float4 kx = *(const float4*)&k_s[kk][xg * 4];
#pragma unroll
      for (int i = 0; i < 4; ++i) {
        float q = qv[i][kk];
        s0[i] += q * kx.x; s1[i] += q * kx.y; s2[i] += q * kx.z; s3[i] += q * kx.w;
      }
    }
    // exp (no max), accumulate partial row sums, store P natural [q][m]
#pragma unroll
    for (int i = 0; i < 4; ++i) {
      float p0 = __expf(s0[i]), p1 = __expf(s1[i]);
      float p2 = __expf(s2[i]), p3 = __expf(s3[i]);
      l[i] += p0 + p1 + p2 + p3;
      float4 w4; w4.x = p0; w4.y = p1; w4.z = p2; w4.w = p3;
      *(float4*)&p_s[qg * 4 + i][xg * 4] = w4;
    }
    // commit V regs to LDS
    {
      float* vd = v_s + tid * 4;
      *(float4*)(vd +    0) = vr0;
      *(float4*)(vd + 1024) = vr1;
      *(float4*)(vd + 2048) = vr2;
      *(float4*)(vd + 3072) = vr3;
    }
    __syncthreads();   // p_s + v_s ready

    // PV: o[q][c] for c = xg*4..+3; p reads broadcast, v reads 2-way
#pragma unroll 2
    for (int mm = 0; mm < 16; ++mm) {
      float4 pr0 = *(const float4*)&p_s[qg * 4 + 0][mm * 4];
      float4 pr1 = *(const float4*)&p_s[qg * 4 + 1][mm * 4];
      float4 pr2 = *(const float4*)&p_s[qg * 4 + 2][mm * 4];
      float4 pr3 = *(const float4*)&p_s[qg * 4 + 3][mm * 4];
      float4 vv0 = *(const float4*)&v_s[(mm * 4 + 0) * 64 + xg * 4];
      float4 vv1 = *(const float4*)&v_s[(mm * 4 + 1) * 64 + xg * 4];
      float4 vv2 = *(const float4*)&v_s[(mm * 4 + 2) * 64 + xg * 4];
      float4 vv3 = *(const float4*)&v_s[(mm * 4 + 3) * 64 + xg * 4];
      o[0][0] += pr0.x*vv0.x + pr0.y*vv1.x + pr0.z*vv2.x + pr0.w*vv3.x;
      o[0][1] += pr0.x*vv0.y + pr0.y*vv1.y + pr0.z*vv2.y + pr0.w*vv3.y;
      o[0][2] += pr0.x*vv0.z + pr0.y*vv1.z + pr0.z*vv2.z + pr0.w*vv3.z;
      o[0][3] += pr0.x*vv0.w + pr0.y*vv1.w + pr0.z*vv2.w + pr0.w*vv3.w;
      o[1][0] += pr1.x*vv0.x + pr1.y*vv1.x + pr1.z*vv2.x + pr1.w*vv3.x;
      o[1][1] += pr1.x*vv0.y + pr1.y*vv1.y + pr1.z*vv2.y + pr1.w*vv3.y;
      o[1][2] += pr1.x*vv0.z + pr1.y*vv1.z + pr1.z*vv2.z + pr1.w*vv3.z;
      o[1][3] += pr1.x*vv0.w + pr1.y*vv1.w + pr1.z*vv2.w + pr1.w*vv3.w;
      o[2][0] += pr2.x*vv0.x + pr2.y*vv1.x + pr2.z*vv2.x + pr2.w*vv3.x;
      o[2][1] += pr2.x*vv0.y + pr2.y*vv1.y + pr2.z*vv2.y + pr2.w*vv3.y;
      o[2][2] += pr2.x*vv0.z + pr2.y*vv1.z + pr2.z*vv2.z + pr2.w*vv3.z;
      o[2][3] += pr2.x*vv0.w + pr2.y*vv1.w + pr2.z*vv2.w + pr2.w*vv3.w;
      o[3][0] += pr3.x*vv0.x + pr3.y*vv1.x + pr3.z*vv2.x + pr3.w*vv3.x;
      o[3][1] += pr3.x*vv0.y + pr3.y*vv1.y + pr3.z*vv2.y + pr3.w*vv3.y;
      o[3][2] += pr3.x*vv0.z + pr3.y*vv1.z + pr3.z*vv2.z + pr3.w*vv3.z;
      o[3][3] += pr3.x*vv0.w + pr3.y*vv1.w + pr3.z*vv2.w + pr3.w*vv3.w;
    }
    __syncthreads();   // protect p_s/v_s until all waves' PV done
  }

  // reduce l over the 16 xg-lanes (same qg)
#pragma unroll
  for (int i = 0; i < 4; ++i) {
#pragma unroll
    for (int d = 1; d < 16; d <<= 1) l[i] += __shfl_xor(l[i], d);
  }

  // transpose o into o_s[c][q] (reuse p_s), then linear global writes
#pragma unroll
  for (int j = 0; j < 4; ++j) {
    float4 w4;
    w4.x = o[0][j]; w4.y = o[1][j]; w4.z = o[2][j]; w4.w = o[3][j];
    *(float4*)&p_s[xg * 4 + j][qg * 4] = w4;
  }
  __syncthreads();
  float* obase = o_part + (long)split * 1048576 + ((long)b * 64) * 4096 + n0;
  for (int idx = tid; idx < 4096; idx += 256) {
    int c = idx >> 6, q = idx & 63;
    obase[(long)c * 4096 + q] = p_s[c][q];
  }
  if (xg == 0) {
    float4 lw; lw.x = l[0]; lw.y = l[1]; lw.z = l[2]; lw.w = l[3];
    *(float4*)&l_part[((long)split * 4 + b) * 4096 + n0 + qg * 4] = lw;
  }
}

// ============== attention combine: out = g * (Σo)/(Σl) + x ==================
__global__ __launch_bounds__(256) void k_attnfin(
    const float* __restrict__ op, const float* __restrict__ lp,
    const float* __restrict__ xb, const float* __restrict__ gamma_p,
    float* __restrict__ outb)
{
  int idx = blockIdx.x * 256 + threadIdx.x;   // covers 4*64*4096 = 1048576
  int n = idx & 4095;
  int b = idx >> 18;                           // idx / (64*4096)
  float g = gamma_p[0];
  float o = op[idx] + op[idx + 1048576] + op[idx + 2097152] + op[idx + 3145728];
  const float* lb = lp + b * 4096 + n;
  float l = lb[0] + lb[16384] + lb[32768] + lb[49152];
  outb[idx] = g * o / l + xb[idx];
}

// ================= adaptive avg pool to 8x8 ================================
__global__ __launch_bounds__(256) void k_pool8(
    const float* __restrict__ in, float* __restrict__ out, int B, int C, int H, int W)
{
  int idx = blockIdx.x * 256 + threadIdx.x;
  int total = B * C * 64;
  if (idx >= total) return;
  int ow = idx & 7, oh = (idx >> 3) & 7;
  int c = (idx >> 6) % C, b = idx / (64 * C);
  int bh = H / 8, bw = W / 8;
  const float* src = in + ((long)(b * C + c)) * H * W;
  float s = 0.f;
  for (int y = 0; y < bh; ++y)
    for (int x = 0; x < bw; ++x)
      s += src[(oh * bh + y) * W + ow * bw + x];
  out[idx] = s / (float)(bh * bw);
}

// ================= fc + relu (wave per output) ==============================
__global__ __launch_bounds__(256) void k_fc_relu(
    const float* __restrict__ in, const float* __restrict__ w,
    const float* __restrict__ bias, float* __restrict__ out, int B, int K, int O)
{
  int gi = blockIdx.x * 4 + (threadIdx.x >> 6);
  int lane = threadIdx.x & 63;
  if (gi >= B * O) return;
  int b = gi / O, o = gi % O;
  const float* x = in + (long)b * K;
  const float* wp = w + (long)o * K;
  float s = 0.f;
  for (int i = lane; i < K; i += 64) s += x[i] * wp[i];
#pragma unroll
  for (int d = 1; d < 64; d <<= 1) s += __shfl_xor(s, d);
  if (lane == 0) out[gi] = fmaxf(s + bias[o], 0.f);
}

// ================= line filter: per-row std -> sigmoid mask =================
__global__ __launch_bounds__(256) void k_lf_rowstat(
    const float* __restrict__ x, float* __restrict__ mask_raw, int rows, int W)
{
  int row = blockIdx.x * 4 + (threadIdx.x >> 6);
  int lane = threadIdx.x & 63;
  if (row >= rows) return;
  const float* p = x + (long)row * W;
  float s = 0.f;
  for (int i = lane; i < W; i += 64) s += p[i];
#pragma unroll
  for (int d = 1; d < 64; d <<= 1) s += __shfl_xor(s, d);
  float mean = s / (float)W;
  float v = 0.f;
  for (int i = lane; i < W; i += 64) { float t = p[i] - mean; v += t * t; }
#pragma unroll
  for (int d = 1; d < 64; d <<= 1) v += __shfl_xor(v, d);
  float stdv = sqrtf(v / (float)(W - 1));
  float mask = 1.f / (1.f + __expf(-(0.05f - stdv) * 10.f));
  if (lane == 0) mask_raw[row] = mask;
}

// ================= line filter apply (+optional tanh) =======================
__global__ __launch_bounds__(256) void k_lf_apply(
    const float* __restrict__ x, const float* __restrict__ mask_raw,
    float* __restrict__ out, int BC, int H, int W, float strength, int do_tanh)
{
  long idx = (long)blockIdx.x * 256 + threadIdx.x;
  long total = (long)BC * H * W;
  if (idx >= total) return;
  int wcol = (int)(idx % W);
  int h = (int)((idx / W) % H);
  int bc = (int)(idx / ((long)W * H));
  const float* px = x + (long)bc * H * W;
  const float* pm = mask_raw + (long)bc * H;
  float vs = 0.f, mb = 0.f;
#pragma unroll
  for (int d = -2; d <= 2; ++d) {
    int hh = h + d; hh = hh < 0 ? 0 : (hh >= H ? H - 1 : hh);
    vs += px[hh * W + wcol];
    mb += pm[hh];
  }
  vs *= 0.2f; mb *= 0.2f;
  float m = mb * strength;
  float o = x[idx] * (1.f - m) + vs * m;
  if (do_tanh) o = tanhf(o);
  out[idx] = o;
}

// ---------------- launch ----------------
static inline unsigned gdiv(long total) { return (unsigned)((total + 255) / 256); }

extern "C" void kernel_launch(void* const* d_in, const int* in_sizes, int n_in,
                              void* d_out, int out_size, void* d_ws, size_t ws_size,
                              hipStream_t stream)
{
  (void)in_sizes; (void)n_in; (void)out_size; (void)ws_size;
  const float* sketch   = (const float*)d_in[0];
  const float* depth    = (const float*)d_in[1];
  const float* style    = (const float*)d_in[2];
  const float* enc1_w   = (const float*)d_in[3];
  const float* enc1_b   = (const float*)d_in[4];
  const float* enc2_w   = (const float*)d_in[5];
  const float* enc2_b   = (const float*)d_in[6];
  const float* enc3_w   = (const float*)d_in[7];
  const float* enc3_b   = (const float*)d_in[8];
  const float* se1_w    = (const float*)d_in[9];
  const float* se1_b    = (const float*)d_in[10];
  const float* se2_w    = (const float*)d_in[11];
  const float* se2_b    = (const float*)d_in[12];
  const float* se3_w    = (const float*)d_in[13];
  const float* se3_b    = (const float*)d_in[14];
  const float* sp1_w    = (const float*)d_in[15];
  const float* sp1_b    = (const float*)d_in[16];
  const float* sp2_w    = (const float*)d_in[17];
  const float* sp2_b    = (const float*)d_in[18];
  const float* sm_w     = (const float*)d_in[19];
  const float* sm_b     = (const float*)d_in[20];
  const float* attn_q_w = (const float*)d_in[21];
  const float* attn_q_b = (const float*)d_in[22];
  const float* attn_k_w = (const float*)d_in[23];
  const float* attn_k_b = (const float*)d_in[24];
  const float* attn_v_w = (const float*)d_in[25];
  const float* attn_v_b = (const float*)d_in[26];
  const float* attn_g   = (const float*)d_in[27];
  const float* bn_w     = (const float*)d_in[28];
  const float* bn_b     = (const float*)d_in[29];
  const float* dec3_w   = (const float*)d_in[30];
  const float* dec3_b   = (const float*)d_in[31];
  const float* dec2_w   = (const float*)d_in[32];
  const float* dec2_b   = (const float*)d_in[33];
  const float* dec1_w   = (const float*)d_in[34];
  const float* dec1_b   = (const float*)d_in[35];
  float* out = (float*)d_out;

  float* ws    = (float*)d_ws;
  float* e1    = ws + OFF_E1;
  float* e2    = ws + OFF_E2;
  float* e3a   = ws + OFF_E3A;
  float* e3b   = ws + OFF_E3B;
  float* big16 = ws + OFF_BIG16;   // also attn o_part
  float* big8  = ws + OFF_BIG8;
  float* b4    = ws + OFF_B4;
  float* vbuf  = ws + OFF_V;
  float* qbuf  = ws + OFF_Q;
  float* kbuf  = ws + OFF_K;
  float* pool  = ws + OFF_POOL;
  float* sf1   = ws + OFF_SF1;
  float* sf2   = ws + OFF_SF2;
  float* rowst = ws + OFF_ROW;
  float* d2lf  = ws + OFF_D2LF;    // head doubles as attn l_part
  float* pre   = ws + OFF_PRE;

  const int B = 4;

  // ---- encoder ----
  k_c3<1,1,0, 2, 256,256,1, 2, 16,16, 1,0,0><<<dim3(256, B, 1), 256, 0, stream>>>(
      sketch, depth, enc1_w, enc1_b, nullptr, e1);
  k_c4<16,2,32,8, 256,256, 128,2><<<dim3(64, B, 4), 256, 0, stream>>>(e1, enc2_w, enc2_b, e2);
  k_c4<32,2,64,4, 128,128, 64,4><<<dim3(16, B, 16), 256, 0, stream>>>(e2, enc3_w, enc3_b, e3a);
  k_lf_rowstat<<<(B*64*64 + 3)/4, 256, 0, stream>>>(e3a, rowst, B*64*64, 64);
  k_lf_apply<<<gdiv((long)B*64*64*64), 256, 0, stream>>>(e3a, rowst, e3b, B*64, 64, 64, 0.8f, 0);

  // ---- style branch ----
  k_c3<3,0,0, 3, 256,256,1, 3, 16,16, 1,0,0><<<dim3(256, B, 1), 256, 0, stream>>>(
      style, nullptr, se1_w, se1_b, nullptr, big16);
  k_c4<16,2,32,8, 256,256, 128,2><<<dim3(64, B, 4), 256, 0, stream>>>(big16, se2_w, se2_b, big8);
  k_c4<32,2,64,4, 128,128, 64,4><<<dim3(16, B, 16), 256, 0, stream>>>(big8, se3_w, se3_b, b4);
  k_pool8<<<gdiv(B*64*64), 256, 0, stream>>>(b4, pool, B, 64, 64, 64);
  k_fc_relu<<<(B*64 + 3)/4, 256, 0, stream>>>(pool, sp1_w, sp1_b, sf1, B, 4096, 64);
  k_fc_relu<<<(B*64 + 3)/4, 256, 0, stream>>>(sf1, sp2_w, sp2_b, sf2, B, 64, 64);

  // ---- style merge (+mix fused, bcast channels via wsum) ----
  k_wsum<<<B, 256, 0, stream>>>(sm_w, sf2, pool);
  k_c3<64,0,0, 128, 64,64,4, 8, 64,4, 1,1,1><<<dim3(16, B, 16), 256, 0, stream>>>(
      e3b, nullptr, sm_w, sm_b, pool, e3a);

  // ---- self-attention on e3a -> e3b (KV-split partials + combine) ----
  k_qkproj<<<64, 256, 0, stream>>>(e3a, attn_q_w, attn_q_b, attn_k_w, attn_k_b, qbuf, kbuf, 4096);
  k_vprojT<<<dim3(64, 4), 256, 0, stream>>>(e3a, attn_v_w, attn_v_b, vbuf, 4096);
  k_fattn<<<dim3(64, B, 4), 256, 0, stream>>>(qbuf, kbuf, vbuf, big16, d2lf, 4096);
  k_attnfin<<<4096, 256, 0, stream>>>(big16, d2lf, e3a, attn_g, e3b);

  // ---- bottleneck + decoder ----
  k_c3<64,0,0, 64, 64,64,4, 8, 64,4, 1,0,0><<<dim3(16, B, 16), 256, 0, stream>>>(
      e3b, nullptr, bn_w, bn_b, nullptr, b4);
  k_ct<64,64,32,2, 64,64, 4,4><<<dim3(16, B, 16), 256, 0, stream>>>(b4, e3b, dec3_w, dec3_b, big8);
  k_ct<32,32,16,4, 128,128, 2,4><<<dim3(64, B, 4), 256, 0, stream>>>(big8, e2, dec2_w, dec2_b, big16);
  k_lf_rowstat<<<(B*16*256 + 3)/4, 256, 0, stream>>>(big16, rowst, B*16*256, 256);
  k_lf_apply<<<gdiv((long)B*16*256*256), 256, 0, stream>>>(big16, rowst, d2lf, B*16, 256, 256, 0.8f, 0);
  k_c3<16,16,0, 32, 256,256,1, 8, 3,3, 0,0,0><<<dim3(256, B, 1), 256, 0, stream>>>(
      d2lf, e1, dec1_w, dec1_b, nullptr, pre);
  k_lf_rowstat<<<(B*3*256 + 3)/4, 256, 0, stream>>>(pre, rowst, B*3*256, 256);
  k_lf_apply<<<gdiv((long)B*3*256*256), 256, 0, stream>>>(pre, rowst, out, B*3, 256, 256, 0.9f, 1);
}